// Round 8
// baseline (2421.969 us; speedup 1.0000x reference)
//
#include <hip/hip_runtime.h>
#include <cstddef>

#define TPB 256

typedef _Float16 f16;
typedef _Float16 f16x4 __attribute__((ext_vector_type(4)));
typedef _Float16 f16x8 __attribute__((ext_vector_type(8)));
typedef float f32x4 __attribute__((ext_vector_type(4)));
typedef unsigned long long u64;

// ---------------------------------------------------------------------------
// block reduction (for chanconv)
// ---------------------------------------------------------------------------
__device__ __forceinline__ float block_sum(float v, float* red) {
  int tid = threadIdx.x;
  red[tid] = v; __syncthreads();
#pragma unroll
  for (int off = 128; off > 0; off >>= 1) {
    if (tid < off) red[tid] += red[tid + off];
    __syncthreads();
  }
  float r = red[0];
  __syncthreads();
  return r;
}

// ---------------------------------------------------------------------------
// h0 build: h0[im][4][1024]
// ---------------------------------------------------------------------------
__global__ __launch_bounds__(TPB) void build_h0(const float* __restrict__ kp0,
                                                const float* __restrict__ kp1,
                                                const float* __restrict__ sc0,
                                                const float* __restrict__ sc1,
                                                float* __restrict__ h0) {
  int n = blockIdx.x * TPB + threadIdx.x;
  int im = blockIdx.y;
  const float* kp = im ? kp1 : kp0;
  const float* sc = im ? sc1 : sc0;
  float* h = h0 + (size_t)im * 4096;
  h[n]        = kp[n * 3 + 0];
  h[1024 + n] = kp[n * 3 + 1];
  h[2048 + n] = kp[n * 3 + 2];
  h[3072 + n] = sc[n];
}

// ---------------------------------------------------------------------------
// kenc conv layer (fp32, small)
// ---------------------------------------------------------------------------
template<bool NORMRELU, bool RESID>
__global__ __launch_bounds__(TPB) void chanconv(const float* __restrict__ W,
                                                const float* __restrict__ bias,
                                                const float* __restrict__ in, long instride,
                                                const float* res0, const float* res1,
                                                float* __restrict__ out, long outstride, int C) {
  int o = blockIdx.x, im = blockIdx.y, tid = threadIdx.x;
  const float* inp = in + (long)im * instride;
  __shared__ float Ws[128];
  __shared__ float red[TPB];
  for (int c = tid; c < C; c += TPB) Ws[c] = W[(long)o * C + c];
  __syncthreads();
  float b = bias[o];
  float4 acc = {b, b, b, b};
  for (int c = 0; c < C; ++c) {
    float w = Ws[c];
    float4 v = *(const float4*)(inp + (long)c * 1024 + tid * 4);
    acc.x += w * v.x; acc.y += w * v.y; acc.z += w * v.z; acc.w += w * v.w;
  }
  float* orow = out + (long)im * outstride + (long)o * 1024;
  if (NORMRELU) {
    float s = acc.x + acc.y + acc.z + acc.w;
    float mean = block_sum(s, red) * (1.f / 1024.f);
    float dx = acc.x - mean, dy = acc.y - mean, dz = acc.z - mean, dw = acc.w - mean;
    float var = block_sum(dx * dx + dy * dy + dz * dz + dw * dw, red) * (1.f / 1024.f);
    float rstd = rsqrtf(var + 1e-5f);
    float4 o4 = {fmaxf(dx * rstd, 0.f), fmaxf(dy * rstd, 0.f),
                 fmaxf(dz * rstd, 0.f), fmaxf(dw * rstd, 0.f)};
    *(float4*)(orow + tid * 4) = o4;
  } else {
    if (RESID) {
      const float* res = im ? res1 : res0;
      float4 r = *(const float4*)(res + (long)o * 1024 + tid * 4);
      acc.x += r.x; acc.y += r.y; acc.z += r.z; acc.w += r.w;
    }
    *(float4*)(orow + tid * 4) = acc;
  }
}

// ---------------------------------------------------------------------------
// fp16-MFMA batched GEMM. Block BMxBN, 4 waves, wave (BM==64? 2x2 : 1x4).
// MFMA v_mfma_f32_16x16x16_f16; A-frag lane l: row=l&15, k=4*(l>>4)+j;
// B-frag: col=l&15, same k; D: col=l&15, row=4*(l>>4)+reg.
// ---------------------------------------------------------------------------
struct GBH {
  const void* A; const void* B; const void* B2; void* C;
  const float* bias; const float* res; const float* mu; const float* rs;
  void* o2a; void* o2b; int coff; int pad;
};
struct GB16 { GBH g[16]; };

#define F_BNORM   1
#define F_BCONCAT 2
#define F_BADD    4
#define F_CD16    8
#define F_RES     16
#define F_OUT2    32

template<int BM, int BN, int ASRC, int BSRC, int FLAGS>
__global__ __launch_bounds__(TPB) void gemmh(GB16 gbs, int K, int lda, int ldb,
                                             int ldc, float alpha, int ksplit) {
  constexpr int WM = BM / 32;          // 2 or 1
  constexpr int NWN = 4 / WM;          // waves along N: 2 or 4
  constexpr int WN = BN / NWN;
  constexpr int NFR = WN / 16;
  GBH g = gbs.g[blockIdx.z];
  const int tid = threadIdx.x;
  const int lane = tid & 63, wid = tid >> 6;
  const int wm = wid / NWN, wn = wid % NWN;
  const int m0 = blockIdx.y * BM, n0 = blockIdx.x * BN;
  __shared__ f16 As[BM][36];
  __shared__ f16 Bs[BN][36];
  f32x4 acc[2][NFR];
#pragma unroll
  for (int i = 0; i < 2; ++i)
#pragma unroll
    for (int j = 0; j < NFR; ++j) acc[i][j] = (f32x4){0.f, 0.f, 0.f, 0.f};

  for (int k0 = 0; k0 < K; k0 += 32) {
    // ---- stage A ----
    if constexpr (ASRC == 0) {
      if constexpr (BM == 64) {
        const int m = tid >> 2, k4 = (tid & 3) * 8;
        const float* ap = (const float*)g.A + (long)(m0 + m) * lda + k0 + k4;
        float4 u0 = *(const float4*)ap, u1 = *(const float4*)(ap + 4);
        f16x4 h0 = {(f16)u0.x, (f16)u0.y, (f16)u0.z, (f16)u0.w};
        f16x4 h1 = {(f16)u1.x, (f16)u1.y, (f16)u1.z, (f16)u1.w};
        *(f16x4*)&As[m][k4] = h0;
        *(f16x4*)&As[m][k4 + 4] = h1;
      } else {
        const int m = tid >> 3, k4 = (tid & 7) * 4;
        const float* ap = (const float*)g.A + (long)(m0 + m) * lda + k0 + k4;
        float4 u0 = *(const float4*)ap;
        f16x4 h0 = {(f16)u0.x, (f16)u0.y, (f16)u0.z, (f16)u0.w};
        *(f16x4*)&As[m][k4] = h0;
      }
    } else {  // ASRC == 1: f16 [k][m]
      const int k = tid >> 3, mg = (tid & 7) * 8;
      const f16* ap = (const f16*)g.A + (long)(k0 + k) * lda + m0 + mg;
      f16x8 h = *(const f16x8*)ap;
#pragma unroll
      for (int j = 0; j < 8; ++j) As[mg + j][k] = h[j];
    }
    // ---- stage B ----
#pragma unroll
    for (int r = 0; r < BN / 64; ++r) {
      if constexpr (BSRC == 0) {
        const int k = tid >> 3, ng = (tid & 7) * 8 + r * 64;
        const int kg = k0 + k;
        const float* bp;
        if constexpr ((FLAGS & F_BCONCAT) != 0)
          bp = (kg < ksplit) ? ((const float*)g.B + (long)kg * ldb)
                             : ((const float*)g.B2 + (long)(kg - ksplit) * ldb);
        else
          bp = (const float*)g.B + (long)kg * ldb;
        float4 u0 = *(const float4*)(bp + n0 + ng);
        float4 u1 = *(const float4*)(bp + n0 + ng + 4);
        Bs[ng + 0][k] = (f16)u0.x; Bs[ng + 1][k] = (f16)u0.y;
        Bs[ng + 2][k] = (f16)u0.z; Bs[ng + 3][k] = (f16)u0.w;
        Bs[ng + 4][k] = (f16)u1.x; Bs[ng + 5][k] = (f16)u1.y;
        Bs[ng + 6][k] = (f16)u1.z; Bs[ng + 7][k] = (f16)u1.w;
      } else if constexpr (BSRC == 1) {
        const int k = tid >> 3, ng = (tid & 7) * 8 + r * 64;
        const int kg = k0 + k;
        f16x8 h = *(const f16x8*)((const f16*)g.B + (long)kg * ldb + n0 + ng);
        if constexpr ((FLAGS & F_BNORM) != 0) {
          const float mu = g.mu[kg], rs = g.rs[kg];
#pragma unroll
          for (int j = 0; j < 8; ++j)
            h[j] = (f16)fmaxf(((float)h[j] - mu) * rs, 0.f);
        }
#pragma unroll
        for (int j = 0; j < 8; ++j) Bs[ng + j][k] = h[j];
      } else {  // BSRC == 2: f16 [n][k]
        const int n = (tid >> 2) + r * 64, k4 = (tid & 3) * 8;
        const f16* bp = (const f16*)g.B + (long)(n0 + n) * ldb + k0 + k4;
        f16x8 h = *(const f16x8*)bp;
        if constexpr ((FLAGS & F_BADD) != 0) {
          f16x8 h2 = *(const f16x8*)((const f16*)g.B2 + (long)(n0 + n) * ldb + k0 + k4);
          h = h + h2;
        }
        f16x4 h0 = {h[0], h[1], h[2], h[3]};
        f16x4 h1 = {h[4], h[5], h[6], h[7]};
        *(f16x4*)&Bs[n][k4] = h0;
        *(f16x4*)&Bs[n][k4 + 4] = h1;
      }
    }
    __syncthreads();
    // ---- MFMA ----
#pragma unroll
    for (int ks = 0; ks < 2; ++ks) {
      const int kof = ks * 16 + ((lane >> 4) << 2);
      f16x4 a[2], b[NFR];
      a[0] = *(const f16x4*)&As[wm * 32 + (lane & 15)][kof];
      a[1] = *(const f16x4*)&As[wm * 32 + 16 + (lane & 15)][kof];
#pragma unroll
      for (int fn = 0; fn < NFR; ++fn)
        b[fn] = *(const f16x4*)&Bs[wn * WN + fn * 16 + (lane & 15)][kof];
#pragma unroll
      for (int fm = 0; fm < 2; ++fm)
#pragma unroll
        for (int fn = 0; fn < NFR; ++fn)
          acc[fm][fn] = __builtin_amdgcn_mfma_f32_16x16x16f16(a[fm], b[fn], acc[fm][fn], 0, 0, 0);
    }
    __syncthreads();
  }

  // ---- epilogue ----
  const int r0 = (lane >> 4) << 2, cn = lane & 15;
#pragma unroll
  for (int fm = 0; fm < 2; ++fm) {
#pragma unroll
    for (int r = 0; r < 4; ++r) {
      const int m = m0 + wm * 32 + fm * 16 + r0 + r;
      const float bi = g.bias ? g.bias[m] : 0.f;
#pragma unroll
      for (int fn = 0; fn < NFR; ++fn) {
        const int n = n0 + wn * WN + fn * 16 + cn;
        float v = acc[fm][fn][r] * alpha + bi;
        if constexpr ((FLAGS & F_RES) != 0) v += g.res[(long)m * ldc + n];
        if constexpr ((FLAGS & F_OUT2) != 0) {
          ((float*)g.C)[(long)m * 1028 + n] = v;
          ((f16*)g.o2a)[(long)m * 1028 + n] = (f16)v;
          ((f16*)g.o2b)[(long)n * 1028 + m] = (f16)v;
        } else if constexpr ((FLAGS & F_CD16) != 0) {
          ((f16*)g.C)[(long)m * ldc + n] = (f16)v;
        } else {
          ((float*)g.C)[(long)m * ldc + n] = v;
        }
      }
    }
  }
}

// ---------------------------------------------------------------------------
// Fused attention: per block = (im, head, 16-query tile).
//   phase 1: S[16][1024] = q^T k / 8 into LDS (MFMA, K-tile transposed stage)
//   phase 2: row max/sum; rewrite S := exp(S - m) / sum (f16, in place)
//   phase 3: O = P V^T (V staged coalesced, [d][kv] == MFMA B layout)
//   out: oT[pos][4d+h] f16
// Fragment mappings identical to gemmh (16x16x16 f16 MFMA).
// ---------------------------------------------------------------------------
__global__ __launch_bounds__(TPB) void fused_attn(const f16* __restrict__ qkv,
                                                  f16* __restrict__ oT) {
  const int im = blockIdx.y >> 2, h = blockIdx.y & 3;
  const int q0 = blockIdx.x * 16;
  const long DSTR = 262144;
  const f16* qp = qkv + (long)(im * 3 + 0) * DSTR + h * 1024;
  const f16* kp = qkv + (long)(im * 3 + 1) * DSTR + h * 1024;
  const f16* vp = qkv + (long)(im * 3 + 2) * DSTR + h * 1024;
  f16* op = oT + (long)im * 262144;   // [1024 pos][256 ch]

  __shared__ f16 Qs[16][68];
  __shared__ f16 Ss[16][1032];
  __shared__ f16 KV[8704];            // phase1: [kv][d] pitch 68; phase3: [d][kv] pitch 136

  const int tid = threadIdx.x, lane = tid & 63, w = tid >> 6;
  const int l15 = lane & 15, lh = (lane >> 4) << 2;

  // stage Q: Qs[q][d]
  {
    const int d = tid >> 2, q4 = (tid & 3) * 4;
    f16x4 v4 = *(const f16x4*)(qp + (long)d * 4096 + q0 + q4);
#pragma unroll
    for (int j = 0; j < 4; ++j) Qs[q4 + j][d] = v4[j];
  }

  // ---- phase 1: S = q^T k / 8 ----
  for (int kt = 0; kt < 8; ++kt) {
    const int kv0 = kt * 128;
    __syncthreads();
    // stage K-tile transposed: KV[kv][d], pitch 68
#pragma unroll
    for (int r = 0; r < 4; ++r) {
      const int d = (tid >> 4) + 16 * r, kvg = (tid & 15) * 8;
      f16x8 v8 = *(const f16x8*)(kp + (long)d * 4096 + kv0 + kvg);
#pragma unroll
      for (int j = 0; j < 8; ++j) KV[(kvg + j) * 68 + d] = v8[j];
    }
    __syncthreads();
    f32x4 sacc[2] = {{0.f, 0.f, 0.f, 0.f}, {0.f, 0.f, 0.f, 0.f}};
#pragma unroll
    for (int ks = 0; ks < 4; ++ks) {
      const int kof = ks * 16 + lh;
      f16x4 a  = *(const f16x4*)&Qs[l15][kof];
      f16x4 b0 = *(const f16x4*)&KV[(w * 32 + l15) * 68 + kof];
      f16x4 b1 = *(const f16x4*)&KV[(w * 32 + 16 + l15) * 68 + kof];
      sacc[0] = __builtin_amdgcn_mfma_f32_16x16x16f16(a, b0, sacc[0], 0, 0, 0);
      sacc[1] = __builtin_amdgcn_mfma_f32_16x16x16f16(a, b1, sacc[1], 0, 0, 0);
    }
#pragma unroll
    for (int fn = 0; fn < 2; ++fn) {
      const int kv = kv0 + w * 32 + fn * 16 + l15;
#pragma unroll
      for (int r = 0; r < 4; ++r)
        Ss[lh + r][kv] = (f16)(sacc[fn][r] * 0.125f);
    }
  }
  __syncthreads();

  // ---- phase 2: softmax rows, rewrite P in place ----
#pragma unroll
  for (int rr = 0; rr < 4; ++rr) {
    const int q = w * 4 + rr;
    f16x8 x0 = *(const f16x8*)&Ss[q][lane * 16];
    f16x8 x1 = *(const f16x8*)&Ss[q][lane * 16 + 8];
    float m = -1e30f;
#pragma unroll
    for (int j = 0; j < 8; ++j)
      m = fmaxf(m, fmaxf((float)x0[j], (float)x1[j]));
#pragma unroll
    for (int off = 32; off > 0; off >>= 1) m = fmaxf(m, __shfl_xor(m, off));
    float s = 0.f;
#pragma unroll
    for (int j = 0; j < 8; ++j)
      s += __expf((float)x0[j] - m) + __expf((float)x1[j] - m);
#pragma unroll
    for (int off = 32; off > 0; off >>= 1) s += __shfl_xor(s, off);
    const float inv = 1.f / s;
    f16x8 p0, p1;
#pragma unroll
    for (int j = 0; j < 8; ++j) {
      p0[j] = (f16)(__expf((float)x0[j] - m) * inv);
      p1[j] = (f16)(__expf((float)x1[j] - m) * inv);
    }
    *(f16x8*)&Ss[q][lane * 16] = p0;
    *(f16x8*)&Ss[q][lane * 16 + 8] = p1;
  }

  // ---- phase 3: O = P V^T ----
  f32x4 oacc = {0.f, 0.f, 0.f, 0.f};
  for (int kt = 0; kt < 8; ++kt) {
    __syncthreads();
    // stage V-tile coalesced: KV[d][kv], pitch 136
    {
      const int d = tid >> 2, kvg = (tid & 3) * 32;
#pragma unroll
      for (int j = 0; j < 4; ++j) {
        f16x8 v8 = *(const f16x8*)(vp + (long)d * 4096 + kt * 128 + kvg + j * 8);
        *(f16x8*)&KV[d * 136 + kvg + j * 8] = v8;
      }
    }
    __syncthreads();
#pragma unroll
    for (int ks = 0; ks < 8; ++ks) {
      f16x4 a = *(const f16x4*)&Ss[l15][kt * 128 + ks * 16 + lh];
      f16x4 b = *(const f16x4*)&KV[(w * 16 + l15) * 136 + ks * 16 + lh];
      oacc = __builtin_amdgcn_mfma_f32_16x16x16f16(a, b, oacc, 0, 0, 0);
    }
  }
  // store: lane: d = w*16 + l15; rows q = lh + r
  {
    const int d = w * 16 + l15;
#pragma unroll
    for (int r = 0; r < 4; ++r) {
      const int q = q0 + lh + r;
      op[(long)q * 256 + h + 4 * d] = (f16)oacc[r];
    }
  }
}

// ---------------------------------------------------------------------------
// rowstats over f16 tb rows (1024 wide): mean, rsqrt(var+eps). Wave/row.
// ---------------------------------------------------------------------------
__global__ __launch_bounds__(TPB) void rowstats2_h(const f16* __restrict__ t,
                                                   float* __restrict__ mu,
                                                   float* __restrict__ rs) {
  int row = blockIdx.x * 4 + (threadIdx.x >> 6);
  int lane = threadIdx.x & 63;
  const f16x8* p = (const f16x8*)(t + (long)row * 1024);
  f16x8 v0 = p[lane], v1 = p[lane + 64];
  float s = 0.f, s2 = 0.f;
#pragma unroll
  for (int j = 0; j < 8; ++j) {
    float a = (float)v0[j], b = (float)v1[j];
    s += a + b; s2 += a * a + b * b;
  }
#pragma unroll
  for (int off = 32; off > 0; off >>= 1) { s += __shfl_xor(s, off); s2 += __shfl_xor(s2, off); }
  if (lane == 0) {
    float mean = s * (1.f / 1024.f);
    mu[row] = mean;
    rs[row] = rsqrtf(fmaxf(s2 * (1.f / 1024.f) - mean * mean, 0.f) + 1e-5f);
  }
}

// ---------------------------------------------------------------------------
// Sinkhorn — persistent, Z in registers, relaxed-only grid barrier +
// block-consolidated consume into LDS (r7 design, proven).
// ---------------------------------------------------------------------------
#define NORMC  (-7.62461899f)   /* -log(2048) */
#define LOGN   (6.93147181f)    /* log(1024)  */
#define LOG_MN (7.62461899f)    /* log(2048)  */
#define ZLD    1028
#define SINKB  64

__device__ __forceinline__ u64 llc_load64(const u64* p) {
  return __hip_atomic_load(p, __ATOMIC_RELAXED, __HIP_MEMORY_SCOPE_AGENT);
}
__device__ __forceinline__ void llc_store64(u64* p, u64 v) {
  __hip_atomic_store(p, v, __ATOMIC_RELAXED, __HIP_MEMORY_SCOPE_AGENT);
}
__device__ __forceinline__ void llc_store32(float* p, float v) {
  __hip_atomic_store(p, v, __ATOMIC_RELAXED, __HIP_MEMORY_SCOPE_AGENT);
}
__device__ __forceinline__ u64 pack2(float a, float b) {
  union { float f[2]; u64 x; } c; c.f[0] = a; c.f[1] = b; return c.x;
}

__global__ __launch_bounds__(TPB) void fill_bins(float* __restrict__ Z,
                                                 const float* __restrict__ alpha_p,
                                                 float* __restrict__ vF,
                                                 unsigned* __restrict__ bar) {
  float a = *alpha_p;
  int t = blockIdx.x * TPB + threadIdx.x;
  if (t < ZLD) vF[t] = 0.f;
  if (t == 0) *bar = 0u;
  if (t <= 1024) {
    Z[(long)t * ZLD + 1024] = a;
    Z[(long)1024 * ZLD + t] = a;
  }
}

__device__ __forceinline__ void gridbar(unsigned* __restrict__ bar, unsigned gen) {
  __syncthreads();
  if (threadIdx.x == 0) {
    __hip_atomic_fetch_add(bar, 1u, __ATOMIC_RELAXED, __HIP_MEMORY_SCOPE_AGENT);
    const unsigned target = gen * SINKB;
    while (__hip_atomic_load(bar, __ATOMIC_RELAXED, __HIP_MEMORY_SCOPE_AGENT) < target) {}
  }
  asm volatile("" ::: "memory");
  __syncthreads();
}

__device__ __forceinline__ void sink_half(const f16x8 zreg[4][2],
                                          const float* __restrict__ w,
                                          float* __restrict__ out,
                                          int tid, int gw, int lane,
                                          float alpha, float* __restrict__ lds) {
  for (int s = tid; s < 513; s += TPB) {
    u64 x = llc_load64((const u64*)w + s);
    union { u64 x; float f[2]; } c; c.x = x;
    lds[2 * s] = c.f[0];
    lds[2 * s + 1] = c.f[1];
  }
  __syncthreads();
  float vv[16];
#pragma unroll
  for (int t = 0; t < 16; ++t) vv[t] = lds[lane + 64 * t];
  const float w1024 = lds[1024];
  const float binv = alpha + w1024;

  float res[4];
#pragma unroll
  for (int r = 0; r < 4; ++r) {
    float val[16];
    float m = binv;
#pragma unroll
    for (int t = 0; t < 16; ++t) {
      val[t] = (float)zreg[r][t >> 3][t & 7] + vv[t];
      m = fmaxf(m, val[t]);
    }
#pragma unroll
    for (int off = 32; off > 0; off >>= 1) m = fmaxf(m, __shfl_xor(m, off));
    float s = 0.f;
#pragma unroll
    for (int t = 0; t < 16; ++t) s += __expf(val[t] - m);
#pragma unroll
    for (int off = 32; off > 0; off >>= 1) s += __shfl_xor(s, off);
    s += __expf(binv - m);
    res[r] = NORMC - (m + logf(s));
  }
  if (lane < 2)
    llc_store64((u64*)(out + 4 * gw) + lane, pack2(res[2 * lane], res[2 * lane + 1]));

  if (gw == 0) {
    float m = w1024;
#pragma unroll
    for (int t = 0; t < 16; ++t) m = fmaxf(m, vv[t]);
#pragma unroll
    for (int off = 32; off > 0; off >>= 1) m = fmaxf(m, __shfl_xor(m, off));
    float s = 0.f;
#pragma unroll
    for (int t = 0; t < 16; ++t) s += __expf(vv[t] - m);
#pragma unroll
    for (int off = 32; off > 0; off >>= 1) s += __shfl_xor(s, off);
    s += __expf(w1024 - m);
    if (lane == 0)
      llc_store32(out + 1024, NORMC + LOGN - (alpha + m + logf(s)));
  }
}

__global__ __launch_bounds__(TPB) void sink_persist(const f16* __restrict__ Zh,
                                                    const f16* __restrict__ Zth,
                                                    float* __restrict__ uF,
                                                    float* __restrict__ vF,
                                                    unsigned* __restrict__ bar,
                                                    const float* __restrict__ alpha_p) {
  __shared__ float lds[ZLD];
  const int tid = threadIdx.x;
  const int lane = tid & 63;
  const int gw = blockIdx.x * 4 + (tid >> 6);   // 0..255, owns rows [4gw,4gw+4)
  const float alpha = *alpha_p;

  f16x8 zr[4][2], zt[4][2];
#pragma unroll
  for (int r = 0; r < 4; ++r) {
    const long row = 4 * gw + r;
    const f16* zp = Zh + row * ZLD;
    const f16* ztp = Zth + row * ZLD;
#pragma unroll
    for (int hh = 0; hh < 2; ++hh)
#pragma unroll
      for (int j = 0; j < 8; ++j) {
        zr[r][hh][j] = zp[lane + 64 * (8 * hh + j)];
        zt[r][hh][j] = ztp[lane + 64 * (8 * hh + j)];
      }
  }

  unsigned gen = 0;
#pragma unroll 1
  for (int it = 0; it < 100; ++it) {
    sink_half(zr, vF, uF, tid, gw, lane, alpha, lds);
    gridbar(bar, ++gen);
    sink_half(zt, uF, vF, tid, gw, lane, alpha, lds);
    gridbar(bar, ++gen);
  }
}

__global__ __launch_bounds__(TPB) void assemble(const float* __restrict__ Z,
                                                const float* __restrict__ u,
                                                const float* __restrict__ v,
                                                float* __restrict__ out) {
  int idx = blockIdx.x * TPB + threadIdx.x;
  if (idx < 1025 * 1025) {
    int i = idx / 1025;
    int j = idx - i * 1025;
    out[idx] = Z[(long)i * ZLD + j] + u[i] + v[j] + LOG_MN;
  }
}

// ---------------------------------------------------------------------------
// Host orchestration
// ---------------------------------------------------------------------------
static inline GBH mkgb(const void* A, const void* B, void* C,
                       const float* bias = nullptr, const void* B2 = nullptr,
                       const float* res = nullptr,
                       const float* mu = nullptr, const float* rs = nullptr,
                       int coff = 0, void* o2a = nullptr, void* o2b = nullptr) {
  GBH g; g.A = A; g.B = B; g.B2 = B2; g.C = C; g.bias = bias; g.res = res;
  g.mu = mu; g.rs = rs; g.o2a = o2a; g.o2b = o2b; g.coff = coff; g.pad = 0;
  return g;
}

extern "C" void kernel_launch(void* const* d_in, const int* in_sizes, int n_in,
                              void* d_out, int out_size, void* d_ws, size_t ws_size,
                              hipStream_t stream) {
  const float* kp0     = (const float*)d_in[0];
  const float* kp1     = (const float*)d_in[1];
  const float* desc0   = (const float*)d_in[2];
  const float* desc1   = (const float*)d_in[3];
  const float* sc0     = (const float*)d_in[4];
  const float* sc1     = (const float*)d_in[5];
  const float* kw[4]   = {(const float*)d_in[6], (const float*)d_in[8],
                          (const float*)d_in[10], (const float*)d_in[12]};
  const float* kb[4]   = {(const float*)d_in[7], (const float*)d_in[9],
                          (const float*)d_in[11], (const float*)d_in[13]};
  const float* proj_w  = (const float*)d_in[14];
  const float* proj_b  = (const float*)d_in[15];
  const float* merge_w = (const float*)d_in[16];
  const float* merge_b = (const float*)d_in[17];
  const float* mlp_w0  = (const float*)d_in[18];
  const float* mlp_b0  = (const float*)d_in[19];
  const float* mlp_w1  = (const float*)d_in[20];
  const float* mlp_b1  = (const float*)d_in[21];
  const float* final_w = (const float*)d_in[22];
  const float* final_b = (const float*)d_in[23];
  const float* alpha_p = (const float*)d_in[24];

  float* p = (float*)d_ws;
  float* dA  = p; p += 524288;
  float* dB  = p; p += 524288;
  float* h0  = p; p += 8192;
  float* hb1 = p; p += 262144;
  float* hb2 = p; p += 131072;
  float* msg = p; p += 524288;
  float* muA = p; p += 1024;
  float* rsA = p; p += 1024;
  float* Zb  = p; p += 1053700;
  float* uF  = p; p += 1028;
  float* vF  = p; p += 1028;
  unsigned* bar = (unsigned*)p; p += 4;
  f16* qkvh = (f16*)p; p += 786432;   // 6 x 256 x 1024 f16
  f16* oTh  = (f16*)p; p += 262144;   // 2 x 1024 x 256 f16
  f16* tbh  = (f16*)p; p += 524288;   // 2 x 512 x 1024 f16
  f16* mdbh = (f16*)p; p += 262144;   // 2 x 256 x 1024 f16
  f16* Zh   = (f16*)p; p += 526852;
  f16* Zth  = (f16*)p; p += 526852;
  size_t need_bytes = (size_t)(p - (float*)d_ws) * sizeof(float);
  if (ws_size < need_bytes) return;

  const long DSTR = 262144;

  // ---- keypoint encoder ----
  build_h0<<<dim3(4, 2), TPB, 0, stream>>>(kp0, kp1, sc0, sc1, h0);
  chanconv<true, false><<<dim3(32, 2),  TPB, 0, stream>>>(kw[0], kb[0], h0,  4096,   nullptr, nullptr, hb1, 32768,  4);
  chanconv<true, false><<<dim3(64, 2),  TPB, 0, stream>>>(kw[1], kb[1], hb1, 32768,  nullptr, nullptr, hb2, 65536,  32);
  chanconv<true, false><<<dim3(128, 2), TPB, 0, stream>>>(kw[2], kb[2], hb2, 65536,  nullptr, nullptr, hb1, 131072, 64);
  chanconv<false, true><<<dim3(256, 2), TPB, 0, stream>>>(kw[3], kb[3], hb1, 131072, desc0,   desc1,   dA,  DSTR,   128);

  // ---- GNN layers ----
  float* dc = dA;
  float* dn = dB;
  for (int i = 0; i < 18; ++i) {
    bool cross = (i & 1) != 0;
    const float* xs[2] = {dc, dc + DSTR};
    const float* ss2[2] = {cross ? xs[1] : xs[0], cross ? xs[0] : xs[1]};

    // K1: q/k/v projections -> qkvh f16
    {
      GB16 gb{};
      for (int im = 0; im < 2; ++im)
        for (int pp = 0; pp < 3; ++pp)
          gb.g[im * 3 + pp] = mkgb(proj_w + (size_t)(i * 3 + pp) * 65536,
                                   (pp == 0 ? xs[im] : ss2[im]),
                                   qkvh + (size_t)(im * 3 + pp) * DSTR,
                                   proj_b + (size_t)(i * 3 + pp) * 256);
      gemmh<32, 128, 0, 0, F_CD16><<<dim3(8, 8, 6), TPB, 0, stream>>>(
          gb, 256, 256, 1024, 1024, 1.f, 0);
    }
    // K2-4 fused: attention -> oTh [pos][256ch] f16
    fused_attn<<<dim3(64, 8), TPB, 0, stream>>>(qkvh, oTh);
    // K5: merge -> msg fp32
    {
      GB16 gb{};
      for (int im = 0; im < 2; ++im)
        gb.g[im] = mkgb(merge_w + (size_t)i * 65536, oTh + (size_t)im * 262144,
                        msg + (size_t)im * DSTR, merge_b + (size_t)i * 256);
      gemmh<32, 64, 0, 2, 0><<<dim3(16, 8, 2), TPB, 0, stream>>>(
          gb, 256, 256, 256, 1024, 1.f, 0);
    }
    // K6: mlp0 on concat([x, msg]) -> tbh f16
    {
      GB16 gb{};
      for (int im = 0; im < 2; ++im)
        gb.g[im] = mkgb(mlp_w0 + (size_t)i * 262144, xs[im],
                        tbh + (size_t)im * 524288, mlp_b0 + (size_t)i * 512,
                        msg + (size_t)im * DSTR);
      gemmh<64, 64, 0, 0, F_BCONCAT | F_CD16><<<dim3(16, 8, 2), TPB, 0, stream>>>(
          gb, 512, 512, 1024, 1024, 1.f, 256);
    }
    // K7: per-channel inorm stats
    rowstats2_h<<<256, TPB, 0, stream>>>(tbh, muA, rsA);
    // K8: mlp1 with fused inorm+relu on B, fp32 residual -> dn
    {
      GB16 gb{};
      for (int im = 0; im < 2; ++im)
        gb.g[im] = mkgb(mlp_w1 + (size_t)i * 131072, tbh + (size_t)im * 524288,
                        dn + (size_t)im * DSTR, mlp_b1 + (size_t)i * 256,
                        nullptr, xs[im],
                        muA + (size_t)im * 512, rsA + (size_t)im * 512);
      gemmh<32, 64, 0, 1, F_BNORM | F_RES><<<dim3(16, 8, 2), TPB, 0, stream>>>(
          gb, 512, 512, 1024, 1024, 1.f, 0);
    }
    float* tmp = dc; dc = dn; dn = tmp;
  }

  // ---- final projection -> mdbh f16 ----
  {
    GB16 gb{};
    for (int im = 0; im < 2; ++im)
      gb.g[im] = mkgb(final_w, dc + (size_t)im * DSTR, mdbh + (size_t)im * 262144,
                      final_b);
    gemmh<32, 64, 0, 0, F_CD16><<<dim3(16, 8, 2), TPB, 0, stream>>>(
        gb, 256, 256, 1024, 1024, 1.f, 0);
  }
  // ---- scores -> Zb fp32 + Zh/Zth f16 ----
  {
    GB16 gb{};
    gb.g[0] = mkgb(mdbh, mdbh + 262144, Zb, nullptr, nullptr, nullptr,
                   nullptr, nullptr, 0, Zh, Zth);
    gemmh<64, 64, 1, 1, F_OUT2><<<dim3(16, 16, 1), TPB, 0, stream>>>(
        gb, 256, 1024, 1024, ZLD, 0.0625f, 0);
  }
  fill_bins<<<5, TPB, 0, stream>>>(Zb, alpha_p, vF, bar);

  // ---- Sinkhorn: persistent kernel ----
  sink_persist<<<SINKB, TPB, 0, stream>>>(Zh, Zth, uF, vF, bar, alpha_p);

  // ---- output ----
  assemble<<<4105, TPB, 0, stream>>>(Zb, uF, vF, (float*)d_out);
}

// Round 9
// 2277.234 us; speedup vs baseline: 1.0636x; 1.0636x over previous
//
#include <hip/hip_runtime.h>
#include <cstddef>

#define TPB 256

typedef _Float16 f16;
typedef _Float16 f16x4 __attribute__((ext_vector_type(4)));
typedef _Float16 f16x8 __attribute__((ext_vector_type(8)));
typedef float f32x4 __attribute__((ext_vector_type(4)));
typedef unsigned long long u64;

// ---------------------------------------------------------------------------
// block reduction (for chanconv)
// ---------------------------------------------------------------------------
__device__ __forceinline__ float block_sum(float v, float* red) {
  int tid = threadIdx.x;
  red[tid] = v; __syncthreads();
#pragma unroll
  for (int off = 128; off > 0; off >>= 1) {
    if (tid < off) red[tid] += red[tid + off];
    __syncthreads();
  }
  float r = red[0];
  __syncthreads();
  return r;
}

// ---------------------------------------------------------------------------
// h0 build: h0[im][4][1024]
// ---------------------------------------------------------------------------
__global__ __launch_bounds__(TPB) void build_h0(const float* __restrict__ kp0,
                                                const float* __restrict__ kp1,
                                                const float* __restrict__ sc0,
                                                const float* __restrict__ sc1,
                                                float* __restrict__ h0) {
  int n = blockIdx.x * TPB + threadIdx.x;
  int im = blockIdx.y;
  const float* kp = im ? kp1 : kp0;
  const float* sc = im ? sc1 : sc0;
  float* h = h0 + (size_t)im * 4096;
  h[n]        = kp[n * 3 + 0];
  h[1024 + n] = kp[n * 3 + 1];
  h[2048 + n] = kp[n * 3 + 2];
  h[3072 + n] = sc[n];
}

// ---------------------------------------------------------------------------
// kenc conv layer (fp32, small)
// ---------------------------------------------------------------------------
template<bool NORMRELU, bool RESID>
__global__ __launch_bounds__(TPB) void chanconv(const float* __restrict__ W,
                                                const float* __restrict__ bias,
                                                const float* __restrict__ in, long instride,
                                                const float* res0, const float* res1,
                                                float* __restrict__ out, long outstride, int C) {
  int o = blockIdx.x, im = blockIdx.y, tid = threadIdx.x;
  const float* inp = in + (long)im * instride;
  __shared__ float Ws[128];
  __shared__ float red[TPB];
  for (int c = tid; c < C; c += TPB) Ws[c] = W[(long)o * C + c];
  __syncthreads();
  float b = bias[o];
  float4 acc = {b, b, b, b};
  for (int c = 0; c < C; ++c) {
    float w = Ws[c];
    float4 v = *(const float4*)(inp + (long)c * 1024 + tid * 4);
    acc.x += w * v.x; acc.y += w * v.y; acc.z += w * v.z; acc.w += w * v.w;
  }
  float* orow = out + (long)im * outstride + (long)o * 1024;
  if (NORMRELU) {
    float s = acc.x + acc.y + acc.z + acc.w;
    float mean = block_sum(s, red) * (1.f / 1024.f);
    float dx = acc.x - mean, dy = acc.y - mean, dz = acc.z - mean, dw = acc.w - mean;
    float var = block_sum(dx * dx + dy * dy + dz * dz + dw * dw, red) * (1.f / 1024.f);
    float rstd = rsqrtf(var + 1e-5f);
    float4 o4 = {fmaxf(dx * rstd, 0.f), fmaxf(dy * rstd, 0.f),
                 fmaxf(dz * rstd, 0.f), fmaxf(dw * rstd, 0.f)};
    *(float4*)(orow + tid * 4) = o4;
  } else {
    if (RESID) {
      const float* res = im ? res1 : res0;
      float4 r = *(const float4*)(res + (long)o * 1024 + tid * 4);
      acc.x += r.x; acc.y += r.y; acc.z += r.z; acc.w += r.w;
    }
    *(float4*)(orow + tid * 4) = acc;
  }
}

// ---------------------------------------------------------------------------
// fp16-MFMA batched GEMM. Block BMxBN, 4 waves, wave (BM==64? 2x2 : 1x4).
// MFMA v_mfma_f32_16x16x16_f16; A-frag lane l: row=l&15, k=4*(l>>4)+j;
// B-frag: col=l&15, same k; D: col=l&15, row=4*(l>>4)+reg.
// LDS: As[m][k] / Bs[n][k] with k-contiguous rows, pitch 36 f16.
//   ASRC 0: fp32 [m][k]   1: f16 [k][m]   2: f16 [m][k] + softmax exp (mu=M, rs=inv)
//   BSRC 0: fp32 [k][n] (+concat B2)   1: f16 [k][n] (+inorm-relu)   2: f16 [n][k] (+add B2)
// ---------------------------------------------------------------------------
struct GBH {
  const void* A; const void* B; const void* B2; void* C;
  const float* bias; const float* res; const float* mu; const float* rs;
  void* o2a; void* o2b; int coff; int pad;
};
struct GB16 { GBH g[16]; };

#define F_BNORM   1
#define F_BCONCAT 2
#define F_BADD    4
#define F_CD16    8
#define F_RES     16
#define F_OUT2    32
#define F_CSCAT   64

template<int BM, int BN, int ASRC, int BSRC, int FLAGS>
__global__ __launch_bounds__(TPB) void gemmh(GB16 gbs, int K, int lda, int ldb,
                                             int ldc, float alpha, int ksplit) {
  constexpr int WM = BM / 32;          // 2 or 1
  constexpr int NWN = 4 / WM;          // waves along N: 2 or 4
  constexpr int WN = BN / NWN;
  constexpr int NFR = WN / 16;
  GBH g = gbs.g[blockIdx.z];
  const int tid = threadIdx.x;
  const int lane = tid & 63, wid = tid >> 6;
  const int wm = wid / NWN, wn = wid % NWN;
  const int m0 = blockIdx.y * BM, n0 = blockIdx.x * BN;
  __shared__ f16 As[BM][36];
  __shared__ f16 Bs[BN][36];
  f32x4 acc[2][NFR];
#pragma unroll
  for (int i = 0; i < 2; ++i)
#pragma unroll
    for (int j = 0; j < NFR; ++j) acc[i][j] = (f32x4){0.f, 0.f, 0.f, 0.f};

  for (int k0 = 0; k0 < K; k0 += 32) {
    // ---- stage A ----
    if constexpr (ASRC == 0) {
      if constexpr (BM == 64) {
        const int m = tid >> 2, k4 = (tid & 3) * 8;
        const float* ap = (const float*)g.A + (long)(m0 + m) * lda + k0 + k4;
        float4 u0 = *(const float4*)ap, u1 = *(const float4*)(ap + 4);
        f16x4 h0 = {(f16)u0.x, (f16)u0.y, (f16)u0.z, (f16)u0.w};
        f16x4 h1 = {(f16)u1.x, (f16)u1.y, (f16)u1.z, (f16)u1.w};
        *(f16x4*)&As[m][k4] = h0;
        *(f16x4*)&As[m][k4 + 4] = h1;
      } else {
        const int m = tid >> 3, k4 = (tid & 7) * 4;
        const float* ap = (const float*)g.A + (long)(m0 + m) * lda + k0 + k4;
        float4 u0 = *(const float4*)ap;
        f16x4 h0 = {(f16)u0.x, (f16)u0.y, (f16)u0.z, (f16)u0.w};
        *(f16x4*)&As[m][k4] = h0;
      }
    } else if constexpr (ASRC == 1) {
      const int k = tid >> 3, mg = (tid & 7) * 8;
      const f16* ap = (const f16*)g.A + (long)(k0 + k) * lda + m0 + mg;
      f16x8 h = *(const f16x8*)ap;
#pragma unroll
      for (int j = 0; j < 8; ++j) As[mg + j][k] = h[j];
    } else {
      const int m = tid >> 2, k4 = (tid & 3) * 8;
      const f16* ap = (const f16*)g.A + (long)(m0 + m) * lda + k0 + k4;
      f16x8 h = *(const f16x8*)ap;
      const float M = g.mu[m0 + m], Iv = g.rs[m0 + m];
      f16x4 h0, h1;
#pragma unroll
      for (int j = 0; j < 4; ++j) h0[j] = (f16)(__expf((float)h[j] - M) * Iv);
#pragma unroll
      for (int j = 0; j < 4; ++j) h1[j] = (f16)(__expf((float)h[j + 4] - M) * Iv);
      *(f16x4*)&As[m][k4] = h0;
      *(f16x4*)&As[m][k4 + 4] = h1;
    }
    // ---- stage B ----
#pragma unroll
    for (int r = 0; r < BN / 64; ++r) {
      if constexpr (BSRC == 0) {
        const int k = tid >> 3, ng = (tid & 7) * 8 + r * 64;
        const int kg = k0 + k;
        const float* bp;
        if constexpr ((FLAGS & F_BCONCAT) != 0)
          bp = (kg < ksplit) ? ((const float*)g.B + (long)kg * ldb)
                             : ((const float*)g.B2 + (long)(kg - ksplit) * ldb);
        else
          bp = (const float*)g.B + (long)kg * ldb;
        float4 u0 = *(const float4*)(bp + n0 + ng);
        float4 u1 = *(const float4*)(bp + n0 + ng + 4);
        Bs[ng + 0][k] = (f16)u0.x; Bs[ng + 1][k] = (f16)u0.y;
        Bs[ng + 2][k] = (f16)u0.z; Bs[ng + 3][k] = (f16)u0.w;
        Bs[ng + 4][k] = (f16)u1.x; Bs[ng + 5][k] = (f16)u1.y;
        Bs[ng + 6][k] = (f16)u1.z; Bs[ng + 7][k] = (f16)u1.w;
      } else if constexpr (BSRC == 1) {
        const int k = tid >> 3, ng = (tid & 7) * 8 + r * 64;
        const int kg = k0 + k;
        f16x8 h = *(const f16x8*)((const f16*)g.B + (long)kg * ldb + n0 + ng);
        if constexpr ((FLAGS & F_BNORM) != 0) {
          const float mu = g.mu[kg], rs = g.rs[kg];
#pragma unroll
          for (int j = 0; j < 8; ++j)
            h[j] = (f16)fmaxf(((float)h[j] - mu) * rs, 0.f);
        }
#pragma unroll
        for (int j = 0; j < 8; ++j) Bs[ng + j][k] = h[j];
      } else {
        const int n = (tid >> 2) + r * 64, k4 = (tid & 3) * 8;
        const f16* bp = (const f16*)g.B + (long)(n0 + n) * ldb + k0 + k4;
        f16x8 h = *(const f16x8*)bp;
        if constexpr ((FLAGS & F_BADD) != 0) {
          f16x8 h2 = *(const f16x8*)((const f16*)g.B2 + (long)(n0 + n) * ldb + k0 + k4);
          h = h + h2;
        }
        f16x4 h0 = {h[0], h[1], h[2], h[3]};
        f16x4 h1 = {h[4], h[5], h[6], h[7]};
        *(f16x4*)&Bs[n][k4] = h0;
        *(f16x4*)&Bs[n][k4 + 4] = h1;
      }
    }
    __syncthreads();
    // ---- MFMA ----
#pragma unroll
    for (int ks = 0; ks < 2; ++ks) {
      const int kof = ks * 16 + ((lane >> 4) << 2);
      f16x4 a[2], b[NFR];
      a[0] = *(const f16x4*)&As[wm * 32 + (lane & 15)][kof];
      a[1] = *(const f16x4*)&As[wm * 32 + 16 + (lane & 15)][kof];
#pragma unroll
      for (int fn = 0; fn < NFR; ++fn)
        b[fn] = *(const f16x4*)&Bs[wn * WN + fn * 16 + (lane & 15)][kof];
#pragma unroll
      for (int fm = 0; fm < 2; ++fm)
#pragma unroll
        for (int fn = 0; fn < NFR; ++fn)
          acc[fm][fn] = __builtin_amdgcn_mfma_f32_16x16x16f16(a[fm], b[fn], acc[fm][fn], 0, 0, 0);
    }
    __syncthreads();
  }

  // ---- epilogue ----
  const int r0 = (lane >> 4) << 2, cn = lane & 15;
#pragma unroll
  for (int fm = 0; fm < 2; ++fm) {
#pragma unroll
    for (int r = 0; r < 4; ++r) {
      const int m = m0 + wm * 32 + fm * 16 + r0 + r;
      const float bi = g.bias ? g.bias[m] : 0.f;
#pragma unroll
      for (int fn = 0; fn < NFR; ++fn) {
        const int n = n0 + wn * WN + fn * 16 + cn;
        float v = acc[fm][fn][r] * alpha + bi;
        if constexpr ((FLAGS & F_RES) != 0) v += g.res[(long)m * ldc + n];
        if constexpr ((FLAGS & F_OUT2) != 0) {
          ((float*)g.C)[(long)m * 1028 + n] = v;
          ((f16*)g.o2a)[(long)m * 1028 + n] = (f16)v;
          ((f16*)g.o2b)[(long)n * 1028 + m] = (f16)v;
        } else if constexpr ((FLAGS & F_CSCAT) != 0) {
          ((f16*)g.C)[(long)m * ldc + g.coff + 4 * n] = (f16)v;
        } else if constexpr ((FLAGS & F_CD16) != 0) {
          ((f16*)g.C)[(long)m * ldc + n] = (f16)v;
        } else {
          ((float*)g.C)[(long)m * ldc + n] = v;
        }
      }
    }
  }
}

// ---------------------------------------------------------------------------
// rowlse over f16 S rows (1024 wide): Mrow, Inv = 1/sum(exp(x-M)). Wave/row.
// ---------------------------------------------------------------------------
__global__ __launch_bounds__(TPB) void rowlse_h(const f16* __restrict__ S,
                                                float* __restrict__ Mrow,
                                                float* __restrict__ Inv) {
  int row = blockIdx.x * 4 + (threadIdx.x >> 6);
  int lane = threadIdx.x & 63;
  const f16x8* p = (const f16x8*)(S + (long)row * 1024);
  f16x8 v0 = p[lane], v1 = p[lane + 64];
  float m = -1e30f;
#pragma unroll
  for (int j = 0; j < 8; ++j)
    m = fmaxf(m, fmaxf((float)v0[j], (float)v1[j]));
#pragma unroll
  for (int off = 32; off > 0; off >>= 1) m = fmaxf(m, __shfl_xor(m, off));
  float s = 0.f;
#pragma unroll
  for (int j = 0; j < 8; ++j)
    s += __expf((float)v0[j] - m) + __expf((float)v1[j] - m);
#pragma unroll
  for (int off = 32; off > 0; off >>= 1) s += __shfl_xor(s, off);
  if (lane == 0) { Mrow[row] = m; Inv[row] = 1.f / s; }
}

// ---------------------------------------------------------------------------
// rowstats over f16 tb rows (1024 wide): mean, rsqrt(var+eps). Wave/row.
// ---------------------------------------------------------------------------
__global__ __launch_bounds__(TPB) void rowstats2_h(const f16* __restrict__ t,
                                                   float* __restrict__ mu,
                                                   float* __restrict__ rs) {
  int row = blockIdx.x * 4 + (threadIdx.x >> 6);
  int lane = threadIdx.x & 63;
  const f16x8* p = (const f16x8*)(t + (long)row * 1024);
  f16x8 v0 = p[lane], v1 = p[lane + 64];
  float s = 0.f, s2 = 0.f;
#pragma unroll
  for (int j = 0; j < 8; ++j) {
    float a = (float)v0[j], b = (float)v1[j];
    s += a + b; s2 += a * a + b * b;
  }
#pragma unroll
  for (int off = 32; off > 0; off >>= 1) { s += __shfl_xor(s, off); s2 += __shfl_xor(s2, off); }
  if (lane == 0) {
    float mean = s * (1.f / 1024.f);
    mu[row] = mean;
    rs[row] = rsqrtf(fmaxf(s2 * (1.f / 1024.f) - mean * mean, 0.f) + 1e-5f);
  }
}

// ---------------------------------------------------------------------------
// Sinkhorn — persistent, Z in registers, BARRIER-FREE with generation-tagged
// slots + block-consolidated consume:
//   u/v = 1025 u64 slots, hi32 = generation, lo32 = fp32 value (relaxed
//   agent-scope 8B atomics -> LLC, bypassing non-coherent per-XCD L2s).
//   Consume: each THREAD spin-loads its own 4-5 slots (coalesced per wave)
//   until tag==gen, deposits into LDS, syncthreads. No redundant per-wave
//   polling (r6's flaw), no barrier counter round-trip (r7's cost).
//   Invariant: a block writes gen g+1 only after consuming ALL of gen g,
//   so gen g+2 never overwrites a slot some block still needs at g.
// ---------------------------------------------------------------------------
#define NORMC  (-7.62461899f)   /* -log(2048) */
#define LOGN   (6.93147181f)    /* log(1024)  */
#define LOG_MN (7.62461899f)    /* log(2048)  */
#define ZLD    1028
#define SINKB  64

__device__ __forceinline__ u64 llc_load64(const u64* p) {
  return __hip_atomic_load(p, __ATOMIC_RELAXED, __HIP_MEMORY_SCOPE_AGENT);
}
__device__ __forceinline__ void slot_store(u64* p, float v, unsigned gen) {
  union { float f; unsigned u; } c; c.f = v;
  u64 x = ((u64)gen << 32) | (u64)c.u;
  __hip_atomic_store(p, x, __ATOMIC_RELAXED, __HIP_MEMORY_SCOPE_AGENT);
}
__device__ __forceinline__ float slot_val(u64 x) {
  union { unsigned u; float f; } c; c.u = (unsigned)x;
  return c.f;
}

__global__ __launch_bounds__(TPB) void fill_bins(float* __restrict__ Z,
                                                 const float* __restrict__ alpha_p,
                                                 u64* __restrict__ uS,
                                                 u64* __restrict__ vS) {
  float a = *alpha_p;
  int t = blockIdx.x * TPB + threadIdx.x;
  if (t <= 1024) {
    Z[(long)t * ZLD + 1024] = a;
    Z[(long)1024 * ZLD + t] = a;
    slot_store(uS + t, 0.f, 0u);   // reset tags every call (graph replays)
    slot_store(vS + t, 0.f, 0u);
  }
}

// one half-step: spin-consume w@rgen into LDS, compute 4 rows/wave (+ bin row
// on wave 0), store tagged results @rgen+1.
__device__ __forceinline__ void sink_half(const f16x8 zreg[4][2],
                                          const u64* __restrict__ w,
                                          u64* __restrict__ out,
                                          unsigned rgen, int tid, int gw, int lane,
                                          float alpha, float* __restrict__ lds) {
  __syncthreads();   // all waves done reading lds from previous half-step
#pragma unroll
  for (int q = 0; q < 4; ++q) {
    const int s = tid + q * TPB;
    u64 x;
    do { x = llc_load64(w + s); } while ((unsigned)(x >> 32) != rgen);
    lds[s] = slot_val(x);
  }
  if (tid == 0) {
    u64 x;
    do { x = llc_load64(w + 1024); } while ((unsigned)(x >> 32) != rgen);
    lds[1024] = slot_val(x);
  }
  __syncthreads();

  float vv[16];
#pragma unroll
  for (int t = 0; t < 16; ++t) vv[t] = lds[lane + 64 * t];
  const float w1024 = lds[1024];
  const float binv = alpha + w1024;
  const unsigned wgen = rgen + 1;

  float res[4];
#pragma unroll
  for (int r = 0; r < 4; ++r) {
    float val[16];
    float m = binv;
#pragma unroll
    for (int t = 0; t < 16; ++t) {
      val[t] = (float)zreg[r][t >> 3][t & 7] + vv[t];
      m = fmaxf(m, val[t]);
    }
#pragma unroll
    for (int off = 32; off > 0; off >>= 1) m = fmaxf(m, __shfl_xor(m, off));
    float s = 0.f;
#pragma unroll
    for (int t = 0; t < 16; ++t) s += __expf(val[t] - m);
#pragma unroll
    for (int off = 32; off > 0; off >>= 1) s += __shfl_xor(s, off);
    s += __expf(binv - m);
    res[r] = NORMC - (m + logf(s));
  }
  // lanes 0..3 store rows 4gw+lane (static-index selection, rule #20)
  float myv = (lane == 0) ? res[0] : (lane == 1) ? res[1]
            : (lane == 2) ? res[2] : res[3];
  if (lane < 4) slot_store(out + 4 * gw + lane, myv, wgen);

  if (gw == 0) {
    // bin row: entries alpha + w[j] (j<1024), corner alpha + w[1024]
    float m = w1024;
#pragma unroll
    for (int t = 0; t < 16; ++t) m = fmaxf(m, vv[t]);
#pragma unroll
    for (int off = 32; off > 0; off >>= 1) m = fmaxf(m, __shfl_xor(m, off));
    float s = 0.f;
#pragma unroll
    for (int t = 0; t < 16; ++t) s += __expf(vv[t] - m);
#pragma unroll
    for (int off = 32; off > 0; off >>= 1) s += __shfl_xor(s, off);
    s += __expf(w1024 - m);
    if (lane == 0)
      slot_store(out + 1024, NORMC + LOGN - (alpha + m + logf(s)), wgen);
  }
}

__global__ __launch_bounds__(TPB) void sink_persist(const f16* __restrict__ Zh,
                                                    const f16* __restrict__ Zth,
                                                    u64* __restrict__ uS,
                                                    u64* __restrict__ vS,
                                                    const float* __restrict__ alpha_p) {
  __shared__ float lds[ZLD];
  const int tid = threadIdx.x;
  const int lane = tid & 63;
  const int gw = blockIdx.x * 4 + (tid >> 6);   // 0..255, owns rows [4gw,4gw+4)
  const float alpha = *alpha_p;

  // load 4 Z-rows and 4 Zt-rows into registers (read once, kept 100 iters)
  f16x8 zr[4][2], zt[4][2];
#pragma unroll
  for (int r = 0; r < 4; ++r) {
    const long row = 4 * gw + r;
    const f16* zp = Zh + row * ZLD;
    const f16* ztp = Zth + row * ZLD;
#pragma unroll
    for (int hh = 0; hh < 2; ++hh)
#pragma unroll
      for (int j = 0; j < 8; ++j) {
        zr[r][hh][j] = zp[lane + 64 * (8 * hh + j)];
        zt[r][hh][j] = ztp[lane + 64 * (8 * hh + j)];
      }
  }

  unsigned gen = 0;
#pragma unroll 1
  for (int it = 0; it < 100; ++it) {
    sink_half(zr, vS, uS, gen, tid, gw, lane, alpha, lds);  ++gen;  // u-step
    sink_half(zt, uS, vS, gen, tid, gw, lane, alpha, lds);  ++gen;  // v-step
  }
}

__global__ __launch_bounds__(TPB) void assemble(const float* __restrict__ Z,
                                                const u64* __restrict__ uS,
                                                const u64* __restrict__ vS,
                                                float* __restrict__ out) {
  int idx = blockIdx.x * TPB + threadIdx.x;
  if (idx < 1025 * 1025) {
    int i = idx / 1025;
    int j = idx - i * 1025;
    out[idx] = Z[(long)i * ZLD + j] + slot_val(uS[i]) + slot_val(vS[j]) + LOG_MN;
  }
}

// ---------------------------------------------------------------------------
// Host orchestration
// ---------------------------------------------------------------------------
static inline GBH mkgb(const void* A, const void* B, void* C,
                       const float* bias = nullptr, const void* B2 = nullptr,
                       const float* res = nullptr,
                       const float* mu = nullptr, const float* rs = nullptr,
                       int coff = 0, void* o2a = nullptr, void* o2b = nullptr) {
  GBH g; g.A = A; g.B = B; g.B2 = B2; g.C = C; g.bias = bias; g.res = res;
  g.mu = mu; g.rs = rs; g.o2a = o2a; g.o2b = o2b; g.coff = coff; g.pad = 0;
  return g;
}

extern "C" void kernel_launch(void* const* d_in, const int* in_sizes, int n_in,
                              void* d_out, int out_size, void* d_ws, size_t ws_size,
                              hipStream_t stream) {
  const float* kp0     = (const float*)d_in[0];
  const float* kp1     = (const float*)d_in[1];
  const float* desc0   = (const float*)d_in[2];
  const float* desc1   = (const float*)d_in[3];
  const float* sc0     = (const float*)d_in[4];
  const float* sc1     = (const float*)d_in[5];
  const float* kw[4]   = {(const float*)d_in[6], (const float*)d_in[8],
                          (const float*)d_in[10], (const float*)d_in[12]};
  const float* kb[4]   = {(const float*)d_in[7], (const float*)d_in[9],
                          (const float*)d_in[11], (const float*)d_in[13]};
  const float* proj_w  = (const float*)d_in[14];
  const float* proj_b  = (const float*)d_in[15];
  const float* merge_w = (const float*)d_in[16];
  const float* merge_b = (const float*)d_in[17];
  const float* mlp_w0  = (const float*)d_in[18];
  const float* mlp_b0  = (const float*)d_in[19];
  const float* mlp_w1  = (const float*)d_in[20];
  const float* mlp_b1  = (const float*)d_in[21];
  const float* final_w = (const float*)d_in[22];
  const float* final_b = (const float*)d_in[23];
  const float* alpha_p = (const float*)d_in[24];

  float* p = (float*)d_ws;
  float* dA  = p; p += 524288;
  float* dB  = p; p += 524288;
  float* h0  = p; p += 8192;
  float* hb1 = p; p += 262144;
  float* hb2 = p; p += 131072;
  float* msg = p; p += 524288;
  float* muA = p; p += 1024;
  float* rsA = p; p += 1024;
  float* Mrw = p; p += 8192;
  float* Inv = p; p += 8192;
  float* Zb  = p; p += 1053700;
  u64* uS = (u64*)p; p += 2056;       // 1025+pad u64 tagged slots
  u64* vS = (u64*)p; p += 2056;
  f16* qkvh = (f16*)p; p += 786432;   // 6 x 256 x 1024 f16
  f16* Sh   = (f16*)p; p += 4194304;  // 8 x 1024 x 1024 f16
  f16* oAh  = (f16*)p; p += 262144;   // 2 x 1024 x 256 f16
  f16* oBh  = (f16*)p; p += 262144;
  f16* tbh  = (f16*)p; p += 524288;   // 2 x 512 x 1024 f16
  f16* mdbh = (f16*)p; p += 262144;   // 2 x 256 x 1024 f16
  f16* Zh   = (f16*)p; p += 526852;
  f16* Zth  = (f16*)p; p += 526852;
  size_t need_bytes = (size_t)(p - (float*)d_ws) * sizeof(float);
  if (ws_size < need_bytes) return;

  const long DSTR = 262144;

  // ---- keypoint encoder ----
  build_h0<<<dim3(4, 2), TPB, 0, stream>>>(kp0, kp1, sc0, sc1, h0);
  chanconv<true, false><<<dim3(32, 2),  TPB, 0, stream>>>(kw[0], kb[0], h0,  4096,   nullptr, nullptr, hb1, 32768,  4);
  chanconv<true, false><<<dim3(64, 2),  TPB, 0, stream>>>(kw[1], kb[1], hb1, 32768,  nullptr, nullptr, hb2, 65536,  32);
  chanconv<true, false><<<dim3(128, 2), TPB, 0, stream>>>(kw[2], kb[2], hb2, 65536,  nullptr, nullptr, hb1, 131072, 64);
  chanconv<false, true><<<dim3(256, 2), TPB, 0, stream>>>(kw[3], kb[3], hb1, 131072, desc0,   desc1,   dA,  DSTR,   128);

  // ---- GNN layers ----
  float* dc = dA;
  float* dn = dB;
  for (int i = 0; i < 18; ++i) {
    bool cross = (i & 1) != 0;
    const float* xs[2] = {dc, dc + DSTR};
    const float* ss2[2] = {cross ? xs[1] : xs[0], cross ? xs[0] : xs[1]};

    // K1: q/k/v projections -> qkvh f16
    {
      GB16 gb{};
      for (int im = 0; im < 2; ++im)
        for (int pp = 0; pp < 3; ++pp)
          gb.g[im * 3 + pp] = mkgb(proj_w + (size_t)(i * 3 + pp) * 65536,
                                   (pp == 0 ? xs[im] : ss2[im]),
                                   qkvh + (size_t)(im * 3 + pp) * DSTR,
                                   proj_b + (size_t)(i * 3 + pp) * 256);
      gemmh<32, 128, 0, 0, F_CD16><<<dim3(8, 8, 6), TPB, 0, stream>>>(
          gb, 256, 256, 1024, 1024, 1.f, 0);
    }
    // K2: S = q^T k / 8 -> Sh f16
    {
      GB16 gb{};
      for (int im = 0; im < 2; ++im)
        for (int h = 0; h < 4; ++h)
          gb.g[im * 4 + h] = mkgb(qkvh + (size_t)(im * 3 + 0) * DSTR + h * 1024,
                                  qkvh + (size_t)(im * 3 + 1) * DSTR + h * 1024,
                                  Sh + (size_t)(im * 4 + h) * 1048576);
      gemmh<64, 128, 1, 1, F_CD16><<<dim3(8, 16, 8), TPB, 0, stream>>>(
          gb, 64, 4096, 4096, 1024, 0.125f, 0);
    }
    // K3: per-row softmax stats
    rowlse_h<<<2048, TPB, 0, stream>>>(Sh, Mrw, Inv);
    // K4T: oT[pos][4*d+h] = sum_kv P * v ; K split in halves -> oAh/oBh
    {
      GB16 gb{};
      for (int kh = 0; kh < 2; ++kh)
        for (int imh = 0; imh < 8; ++imh) {
          int im = imh >> 2, h = imh & 3;
          gb.g[kh * 8 + imh] = mkgb(Sh + (size_t)imh * 1048576 + kh * 512,
                                    qkvh + (size_t)(im * 3 + 2) * DSTR + h * 1024 + kh * 512,
                                    (kh ? oBh : oAh) + (size_t)im * 262144,
                                    nullptr, nullptr, nullptr,
                                    Mrw + imh * 1024, Inv + imh * 1024, h);
        }
      gemmh<64, 64, 2, 2, F_CD16 | F_CSCAT><<<dim3(1, 16, 16), TPB, 0, stream>>>(
          gb, 512, 1024, 4096, 256, 1.f, 0);
    }
    // K5: merge (adds the two K-half partials) -> msg fp32
    {
      GB16 gb{};
      for (int im = 0; im < 2; ++im)
        gb.g[im] = mkgb(merge_w + (size_t)i * 65536, oAh + (size_t)im * 262144,
                        msg + (size_t)im * DSTR, merge_b + (size_t)i * 256,
                        oBh + (size_t)im * 262144);
      gemmh<32, 64, 0, 2, F_BADD><<<dim3(16, 8, 2), TPB, 0, stream>>>(
          gb, 256, 256, 256, 1024, 1.f, 0);
    }
    // K6: mlp0 on concat([x, msg]) -> tbh f16
    {
      GB16 gb{};
      for (int im = 0; im < 2; ++im)
        gb.g[im] = mkgb(mlp_w0 + (size_t)i * 262144, xs[im],
                        tbh + (size_t)im * 524288, mlp_b0 + (size_t)i * 512,
                        msg + (size_t)im * DSTR);
      gemmh<64, 64, 0, 0, F_BCONCAT | F_CD16><<<dim3(16, 8, 2), TPB, 0, stream>>>(
          gb, 512, 512, 1024, 1024, 1.f, 256);
    }
    // K7: per-channel inorm stats
    rowstats2_h<<<256, TPB, 0, stream>>>(tbh, muA, rsA);
    // K8: mlp1 with fused inorm+relu on B, fp32 residual -> dn
    {
      GB16 gb{};
      for (int im = 0; im < 2; ++im)
        gb.g[im] = mkgb(mlp_w1 + (size_t)i * 131072, tbh + (size_t)im * 524288,
                        dn + (size_t)im * DSTR, mlp_b1 + (size_t)i * 256,
                        nullptr, xs[im],
                        muA + (size_t)im * 512, rsA + (size_t)im * 512);
      gemmh<32, 64, 0, 1, F_BNORM | F_RES><<<dim3(16, 8, 2), TPB, 0, stream>>>(
          gb, 512, 512, 1024, 1024, 1.f, 0);
    }
    float* tmp = dc; dc = dn; dn = tmp;
  }

  // ---- final projection -> mdbh f16 ----
  {
    GB16 gb{};
    for (int im = 0; im < 2; ++im)
      gb.g[im] = mkgb(final_w, dc + (size_t)im * DSTR, mdbh + (size_t)im * 262144,
                      final_b);
    gemmh<32, 64, 0, 0, F_CD16><<<dim3(16, 8, 2), TPB, 0, stream>>>(
        gb, 256, 256, 1024, 1024, 1.f, 0);
  }
  // ---- scores -> Zb fp32 + Zh/Zth f16 ----
  {
    GB16 gb{};
    gb.g[0] = mkgb(mdbh, mdbh + 262144, Zb, nullptr, nullptr, nullptr,
                   nullptr, nullptr, 0, Zh, Zth);
    gemmh<64, 64, 1, 1, F_OUT2><<<dim3(16, 16, 1), TPB, 0, stream>>>(
        gb, 256, 1024, 1024, ZLD, 0.0625f, 0);
  }
  fill_bins<<<5, TPB, 0, stream>>>(Zb, alpha_p, uS, vS);

  // ---- Sinkhorn: persistent kernel, barrier-free tagged dataflow ----
  sink_persist<<<SINKB, TPB, 0, stream>>>(Zh, Zth, uS, vS, alpha_p);

  // ---- output ----
  assemble<<<4105, TPB, 0, stream>>>(Zb, uS, vS, (float*)d_out);
}

// Round 10
// 2263.996 us; speedup vs baseline: 1.0698x; 1.0058x over previous
//
#include <hip/hip_runtime.h>
#include <cstddef>

#define TPB 256

typedef _Float16 f16;
typedef _Float16 f16x4 __attribute__((ext_vector_type(4)));
typedef _Float16 f16x8 __attribute__((ext_vector_type(8)));
typedef float f32x4 __attribute__((ext_vector_type(4)));
typedef unsigned long long u64;

// ---------------------------------------------------------------------------
// block reduction (for chanconv)
// ---------------------------------------------------------------------------
__device__ __forceinline__ float block_sum(float v, float* red) {
  int tid = threadIdx.x;
  red[tid] = v; __syncthreads();
#pragma unroll
  for (int off = 128; off > 0; off >>= 1) {
    if (tid < off) red[tid] += red[tid + off];
    __syncthreads();
  }
  float r = red[0];
  __syncthreads();
  return r;
}

// ---------------------------------------------------------------------------
// h0 build: h0[im][4][1024]
// ---------------------------------------------------------------------------
__global__ __launch_bounds__(TPB) void build_h0(const float* __restrict__ kp0,
                                                const float* __restrict__ kp1,
                                                const float* __restrict__ sc0,
                                                const float* __restrict__ sc1,
                                                float* __restrict__ h0) {
  int n = blockIdx.x * TPB + threadIdx.x;
  int im = blockIdx.y;
  const float* kp = im ? kp1 : kp0;
  const float* sc = im ? sc1 : sc0;
  float* h = h0 + (size_t)im * 4096;
  h[n]        = kp[n * 3 + 0];
  h[1024 + n] = kp[n * 3 + 1];
  h[2048 + n] = kp[n * 3 + 2];
  h[3072 + n] = sc[n];
}

// ---------------------------------------------------------------------------
// kenc conv layer (fp32, small)
// ---------------------------------------------------------------------------
template<bool NORMRELU, bool RESID>
__global__ __launch_bounds__(TPB) void chanconv(const float* __restrict__ W,
                                                const float* __restrict__ bias,
                                                const float* __restrict__ in, long instride,
                                                const float* res0, const float* res1,
                                                float* __restrict__ out, long outstride, int C) {
  int o = blockIdx.x, im = blockIdx.y, tid = threadIdx.x;
  const float* inp = in + (long)im * instride;
  __shared__ float Ws[128];
  __shared__ float red[TPB];
  for (int c = tid; c < C; c += TPB) Ws[c] = W[(long)o * C + c];
  __syncthreads();
  float b = bias[o];
  float4 acc = {b, b, b, b};
  for (int c = 0; c < C; ++c) {
    float w = Ws[c];
    float4 v = *(const float4*)(inp + (long)c * 1024 + tid * 4);
    acc.x += w * v.x; acc.y += w * v.y; acc.z += w * v.z; acc.w += w * v.w;
  }
  float* orow = out + (long)im * outstride + (long)o * 1024;
  if (NORMRELU) {
    float s = acc.x + acc.y + acc.z + acc.w;
    float mean = block_sum(s, red) * (1.f / 1024.f);
    float dx = acc.x - mean, dy = acc.y - mean, dz = acc.z - mean, dw = acc.w - mean;
    float var = block_sum(dx * dx + dy * dy + dz * dz + dw * dw, red) * (1.f / 1024.f);
    float rstd = rsqrtf(var + 1e-5f);
    float4 o4 = {fmaxf(dx * rstd, 0.f), fmaxf(dy * rstd, 0.f),
                 fmaxf(dz * rstd, 0.f), fmaxf(dw * rstd, 0.f)};
    *(float4*)(orow + tid * 4) = o4;
  } else {
    if (RESID) {
      const float* res = im ? res1 : res0;
      float4 r = *(const float4*)(res + (long)o * 1024 + tid * 4);
      acc.x += r.x; acc.y += r.y; acc.z += r.z; acc.w += r.w;
    }
    *(float4*)(orow + tid * 4) = acc;
  }
}

// ---------------------------------------------------------------------------
// fp16-MFMA batched GEMM. Block BMxBN, 4 waves, wave (BM==64? 2x2 : 1x4).
// MFMA v_mfma_f32_16x16x16_f16; A-frag lane l: row=l&15, k=4*(l>>4)+j;
// B-frag: col=l&15, same k; D: col=l&15, row=4*(l>>4)+reg.
//   ASRC 0: fp32 [m][k] (+F_ACONCAT: k>=ksplit from o2a fp32 ld=256)
//   ASRC 1: f16 [k][m]
//   ASRC 2: f16 [m][k] + softmax exp (mu=M, rs=inv)
//   BSRC 0: fp32 [k][n] (+F_BMIX: k>=ksplit -> f16 (B2+o2b)[n][k'] ld=256)
//   BSRC 1: f16 [k][n] (+F_BNORM mu/rs | +F_BNORM2 from raw sums)
//   BSRC 2: f16 [n][k] (+F_BADD add B2)
// FLAGS: see defines. F_STATS: epilogue accumulates per-row sum/sumsq into
// g.mu/g.rs via atomicAdd (BM=64, BN=64 only).
// ---------------------------------------------------------------------------
struct GBH {
  const void* A; const void* B; const void* B2; void* C;
  const float* bias; const float* res; const float* mu; const float* rs;
  void* o2a; void* o2b; int coff; int pad;
};
struct GBN { GBH g[18]; };

#define F_BNORM   1
#define F_BCONCAT 2
#define F_BADD    4
#define F_CD16    8
#define F_RES     16
#define F_OUT2    32
#define F_CSCAT   64
#define F_BNORM2  128
#define F_ACONCAT 256
#define F_BMIX    512
#define F_STATS   1024

template<int BM, int BN, int ASRC, int BSRC, int FLAGS>
__global__ __launch_bounds__(TPB) void gemmh(GBN gbs, int K, int lda, int ldb,
                                             int ldc, float alpha, int ksplit) {
  constexpr int WM = BM / 32;          // 2 or 1
  constexpr int NWN = 4 / WM;          // waves along N: 2 or 4
  constexpr int WN = BN / NWN;
  constexpr int NFR = WN / 16;
  GBH g = gbs.g[blockIdx.z];
  const int tid = threadIdx.x;
  const int lane = tid & 63, wid = tid >> 6;
  const int wm = wid / NWN, wn = wid % NWN;
  const int m0 = blockIdx.y * BM, n0 = blockIdx.x * BN;
  __shared__ f16 As[BM][36];
  __shared__ f16 Bs[BN][36];
  f32x4 acc[2][NFR];
#pragma unroll
  for (int i = 0; i < 2; ++i)
#pragma unroll
    for (int j = 0; j < NFR; ++j) acc[i][j] = (f32x4){0.f, 0.f, 0.f, 0.f};

  for (int k0 = 0; k0 < K; k0 += 32) {
    // ---- stage A ----
    if constexpr (ASRC == 0) {
      if constexpr (BM == 64) {
        const int m = tid >> 2, k4 = (tid & 3) * 8;
        const float* ap;
        if constexpr ((FLAGS & F_ACONCAT) != 0) {
          if (k0 >= ksplit)
            ap = (const float*)g.o2a + (long)(m0 + m) * 256 + (k0 - ksplit) + k4;
          else
            ap = (const float*)g.A + (long)(m0 + m) * lda + k0 + k4;
        } else {
          ap = (const float*)g.A + (long)(m0 + m) * lda + k0 + k4;
        }
        float4 u0 = *(const float4*)ap, u1 = *(const float4*)(ap + 4);
        f16x4 h0 = {(f16)u0.x, (f16)u0.y, (f16)u0.z, (f16)u0.w};
        f16x4 h1 = {(f16)u1.x, (f16)u1.y, (f16)u1.z, (f16)u1.w};
        *(f16x4*)&As[m][k4] = h0;
        *(f16x4*)&As[m][k4 + 4] = h1;
      } else {
        const int m = tid >> 3, k4 = (tid & 7) * 4;
        const float* ap = (const float*)g.A + (long)(m0 + m) * lda + k0 + k4;
        float4 u0 = *(const float4*)ap;
        f16x4 h0 = {(f16)u0.x, (f16)u0.y, (f16)u0.z, (f16)u0.w};
        *(f16x4*)&As[m][k4] = h0;
      }
    } else if constexpr (ASRC == 1) {
      const int k = tid >> 3, mg = (tid & 7) * 8;
      const f16* ap = (const f16*)g.A + (long)(k0 + k) * lda + m0 + mg;
      f16x8 h = *(const f16x8*)ap;
#pragma unroll
      for (int j = 0; j < 8; ++j) As[mg + j][k] = h[j];
    } else {
      const int m = tid >> 2, k4 = (tid & 3) * 8;
      const f16* ap = (const f16*)g.A + (long)(m0 + m) * lda + k0 + k4;
      f16x8 h = *(const f16x8*)ap;
      const float M = g.mu[m0 + m], Iv = g.rs[m0 + m];
      f16x4 h0, h1;
#pragma unroll
      for (int j = 0; j < 4; ++j) h0[j] = (f16)(__expf((float)h[j] - M) * Iv);
#pragma unroll
      for (int j = 0; j < 4; ++j) h1[j] = (f16)(__expf((float)h[j + 4] - M) * Iv);
      *(f16x4*)&As[m][k4] = h0;
      *(f16x4*)&As[m][k4 + 4] = h1;
    }
    // ---- stage B ----
#pragma unroll
    for (int r = 0; r < BN / 64; ++r) {
      if constexpr (BSRC == 0) {
        bool f16path = false;
        if constexpr ((FLAGS & F_BMIX) != 0) f16path = (k0 >= ksplit);
        if (f16path) {
          const int n = (tid >> 2) + r * 64, k4b = (tid & 3) * 8;
          const long off = (long)(n0 + n) * 256 + (k0 - ksplit) + k4b;
          f16x8 h = *(const f16x8*)((const f16*)g.B2 + off)
                  + *(const f16x8*)((const f16*)g.o2b + off);
          f16x4 h0 = {h[0], h[1], h[2], h[3]};
          f16x4 h1 = {h[4], h[5], h[6], h[7]};
          *(f16x4*)&Bs[n][k4b] = h0;
          *(f16x4*)&Bs[n][k4b + 4] = h1;
        } else {
          const int k = tid >> 3, ng = (tid & 7) * 8 + r * 64;
          const int kg = k0 + k;
          const float* bp;
          if constexpr ((FLAGS & F_BCONCAT) != 0)
            bp = (kg < ksplit) ? ((const float*)g.B + (long)kg * ldb)
                               : ((const float*)g.B2 + (long)(kg - ksplit) * ldb);
          else
            bp = (const float*)g.B + (long)kg * ldb;
          float4 u0 = *(const float4*)(bp + n0 + ng);
          float4 u1 = *(const float4*)(bp + n0 + ng + 4);
          Bs[ng + 0][k] = (f16)u0.x; Bs[ng + 1][k] = (f16)u0.y;
          Bs[ng + 2][k] = (f16)u0.z; Bs[ng + 3][k] = (f16)u0.w;
          Bs[ng + 4][k] = (f16)u1.x; Bs[ng + 5][k] = (f16)u1.y;
          Bs[ng + 6][k] = (f16)u1.z; Bs[ng + 7][k] = (f16)u1.w;
        }
      } else if constexpr (BSRC == 1) {
        const int k = tid >> 3, ng = (tid & 7) * 8 + r * 64;
        const int kg = k0 + k;
        f16x8 h = *(const f16x8*)((const f16*)g.B + (long)kg * ldb + n0 + ng);
        if constexpr ((FLAGS & (F_BNORM | F_BNORM2)) != 0) {
          float mean, rstd;
          if constexpr ((FLAGS & F_BNORM2) != 0) {
            float s1 = g.mu[kg], s2 = g.rs[kg];
            mean = s1 * (1.f / 1024.f);
            rstd = rsqrtf(fmaxf(s2 * (1.f / 1024.f) - mean * mean, 0.f) + 1e-5f);
          } else {
            mean = g.mu[kg]; rstd = g.rs[kg];
          }
#pragma unroll
          for (int j = 0; j < 8; ++j)
            h[j] = (f16)fmaxf(((float)h[j] - mean) * rstd, 0.f);
        }
#pragma unroll
        for (int j = 0; j < 8; ++j) Bs[ng + j][k] = h[j];
      } else {
        const int n = (tid >> 2) + r * 64, k4 = (tid & 3) * 8;
        const f16* bp = (const f16*)g.B + (long)(n0 + n) * ldb + k0 + k4;
        f16x8 h = *(const f16x8*)bp;
        if constexpr ((FLAGS & F_BADD) != 0) {
          f16x8 h2 = *(const f16x8*)((const f16*)g.B2 + (long)(n0 + n) * ldb + k0 + k4);
          h = h + h2;
        }
        f16x4 h0 = {h[0], h[1], h[2], h[3]};
        f16x4 h1 = {h[4], h[5], h[6], h[7]};
        *(f16x4*)&Bs[n][k4] = h0;
        *(f16x4*)&Bs[n][k4 + 4] = h1;
      }
    }
    __syncthreads();
    // ---- MFMA ----
#pragma unroll
    for (int ks = 0; ks < 2; ++ks) {
      const int kof = ks * 16 + ((lane >> 4) << 2);
      f16x4 a[2], b[NFR];
      a[0] = *(const f16x4*)&As[wm * 32 + (lane & 15)][kof];
      a[1] = *(const f16x4*)&As[wm * 32 + 16 + (lane & 15)][kof];
#pragma unroll
      for (int fn = 0; fn < NFR; ++fn)
        b[fn] = *(const f16x4*)&Bs[wn * WN + fn * 16 + (lane & 15)][kof];
#pragma unroll
      for (int fm = 0; fm < 2; ++fm)
#pragma unroll
        for (int fn = 0; fn < NFR; ++fn)
          acc[fm][fn] = __builtin_amdgcn_mfma_f32_16x16x16f16(a[fm], b[fn], acc[fm][fn], 0, 0, 0);
    }
    __syncthreads();
  }

  // ---- epilogue ----
  const int r0 = (lane >> 4) << 2, cn = lane & 15;
#pragma unroll
  for (int fm = 0; fm < 2; ++fm) {
#pragma unroll
    for (int r = 0; r < 4; ++r) {
      const int m = m0 + wm * 32 + fm * 16 + r0 + r;
      const float bi = g.bias ? g.bias[m] : 0.f;
      float s1 = 0.f, s2 = 0.f;
#pragma unroll
      for (int fn = 0; fn < NFR; ++fn) {
        const int n = n0 + wn * WN + fn * 16 + cn;
        float v = acc[fm][fn][r] * alpha + bi;
        if constexpr ((FLAGS & F_RES) != 0) v += g.res[(long)m * ldc + n];
        if constexpr ((FLAGS & F_OUT2) != 0) {
          ((float*)g.C)[(long)m * 1028 + n] = v;
          ((f16*)g.o2a)[(long)m * 1028 + n] = (f16)v;
          ((f16*)g.o2b)[(long)n * 1028 + m] = (f16)v;
        } else if constexpr ((FLAGS & F_CSCAT) != 0) {
          ((f16*)g.C)[(long)m * ldc + g.coff + 4 * n] = (f16)v;
        } else if constexpr ((FLAGS & F_CD16) != 0) {
          ((f16*)g.C)[(long)m * ldc + n] = (f16)v;
        } else {
          ((float*)g.C)[(long)m * ldc + n] = v;
        }
        if constexpr ((FLAGS & F_STATS) != 0) { s1 += v; s2 += v * v; }
      }
      if constexpr ((FLAGS & F_STATS) != 0) {
#pragma unroll
        for (int off = 1; off < 16; off <<= 1) {
          s1 += __shfl_xor(s1, off);
          s2 += __shfl_xor(s2, off);
        }
        if ((lane & 15) == 0) {
          atomicAdd((float*)g.mu + m, s1);
          atomicAdd((float*)g.rs + m, s2);
        }
      }
    }
  }
}

// ---------------------------------------------------------------------------
// rowlse over f16 S rows (1024 wide): Mrow, Inv = 1/sum(exp(x-M)). Wave/row.
// ---------------------------------------------------------------------------
__global__ __launch_bounds__(TPB) void rowlse_h(const f16* __restrict__ S,
                                                float* __restrict__ Mrow,
                                                float* __restrict__ Inv) {
  int row = blockIdx.x * 4 + (threadIdx.x >> 6);
  int lane = threadIdx.x & 63;
  const f16x8* p = (const f16x8*)(S + (long)row * 1024);
  f16x8 v0 = p[lane], v1 = p[lane + 64];
  float m = -1e30f;
#pragma unroll
  for (int j = 0; j < 8; ++j)
    m = fmaxf(m, fmaxf((float)v0[j], (float)v1[j]));
#pragma unroll
  for (int off = 32; off > 0; off >>= 1) m = fmaxf(m, __shfl_xor(m, off));
  float s = 0.f;
#pragma unroll
  for (int j = 0; j < 8; ++j)
    s += __expf((float)v0[j] - m) + __expf((float)v1[j] - m);
#pragma unroll
  for (int off = 32; off > 0; off >>= 1) s += __shfl_xor(s, off);
  if (lane == 0) { Mrow[row] = m; Inv[row] = 1.f / s; }
}

// ---------------------------------------------------------------------------
// weight pre-fusion helpers
// ---------------------------------------------------------------------------
__global__ __launch_bounds__(TPB) void zero_buf(float* __restrict__ p, int n) {
  int i = blockIdx.x * TPB + threadIdx.x;
  if (i < n) p[i] = 0.f;
}

// bf[l][m] = mlp_b0[l][m] + dot(mlp_w0[l][m][256:512], merge_b[l])
__global__ __launch_bounds__(TPB) void bf_prep(const float* __restrict__ mlp_w0,
                                               const float* __restrict__ mlp_b0,
                                               const float* __restrict__ merge_b,
                                               float* __restrict__ bfB) {
  int idx = blockIdx.x * TPB + threadIdx.x;   // 0..9215
  int l = idx >> 9, m = idx & 511;
  const float* wrow = mlp_w0 + (size_t)l * 262144 + (size_t)m * 512 + 256;
  const float* mb = merge_b + (size_t)l * 256;
  float s = mlp_b0[(size_t)l * 512 + m];
  for (int j = 0; j < 256; ++j) s += wrow[j] * mb[j];
  bfB[idx] = s;
}

// ---------------------------------------------------------------------------
// Sinkhorn — persistent, Z in registers, barrier-free generation-tagged slots
// + block-consolidated consume (r9 design, proven best).
// ---------------------------------------------------------------------------
#define NORMC  (-7.62461899f)   /* -log(2048) */
#define LOGN   (6.93147181f)    /* log(1024)  */
#define LOG_MN (7.62461899f)    /* log(2048)  */
#define ZLD    1028
#define SINKB  64

__device__ __forceinline__ u64 llc_load64(const u64* p) {
  return __hip_atomic_load(p, __ATOMIC_RELAXED, __HIP_MEMORY_SCOPE_AGENT);
}
__device__ __forceinline__ void slot_store(u64* p, float v, unsigned gen) {
  union { float f; unsigned u; } c; c.f = v;
  u64 x = ((u64)gen << 32) | (u64)c.u;
  __hip_atomic_store(p, x, __ATOMIC_RELAXED, __HIP_MEMORY_SCOPE_AGENT);
}
__device__ __forceinline__ float slot_val(u64 x) {
  union { unsigned u; float f; } c; c.u = (unsigned)x;
  return c.f;
}

__global__ __launch_bounds__(TPB) void fill_bins(float* __restrict__ Z,
                                                 const float* __restrict__ alpha_p,
                                                 u64* __restrict__ uS,
                                                 u64* __restrict__ vS) {
  float a = *alpha_p;
  int t = blockIdx.x * TPB + threadIdx.x;
  if (t <= 1024) {
    Z[(long)t * ZLD + 1024] = a;
    Z[(long)1024 * ZLD + t] = a;
    slot_store(uS + t, 0.f, 0u);
    slot_store(vS + t, 0.f, 0u);
  }
}

__device__ __forceinline__ void sink_half(const f16x8 zreg[4][2],
                                          const u64* __restrict__ w,
                                          u64* __restrict__ out,
                                          unsigned rgen, int tid, int gw, int lane,
                                          float alpha, float* __restrict__ lds) {
  __syncthreads();
#pragma unroll
  for (int q = 0; q < 4; ++q) {
    const int s = tid + q * TPB;
    u64 x;
    do { x = llc_load64(w + s); } while ((unsigned)(x >> 32) != rgen);
    lds[s] = slot_val(x);
  }
  if (tid == 0) {
    u64 x;
    do { x = llc_load64(w + 1024); } while ((unsigned)(x >> 32) != rgen);
    lds[1024] = slot_val(x);
  }
  __syncthreads();

  float vv[16];
#pragma unroll
  for (int t = 0; t < 16; ++t) vv[t] = lds[lane + 64 * t];
  const float w1024 = lds[1024];
  const float binv = alpha + w1024;
  const unsigned wgen = rgen + 1;

  float res[4];
#pragma unroll
  for (int r = 0; r < 4; ++r) {
    float val[16];
    float m = binv;
#pragma unroll
    for (int t = 0; t < 16; ++t) {
      val[t] = (float)zreg[r][t >> 3][t & 7] + vv[t];
      m = fmaxf(m, val[t]);
    }
#pragma unroll
    for (int off = 32; off > 0; off >>= 1) m = fmaxf(m, __shfl_xor(m, off));
    float s = 0.f;
#pragma unroll
    for (int t = 0; t < 16; ++t) s += __expf(val[t] - m);
#pragma unroll
    for (int off = 32; off > 0; off >>= 1) s += __shfl_xor(s, off);
    s += __expf(binv - m);
    res[r] = NORMC - (m + logf(s));
  }
  float myv = (lane == 0) ? res[0] : (lane == 1) ? res[1]
            : (lane == 2) ? res[2] : res[3];
  if (lane < 4) slot_store(out + 4 * gw + lane, myv, wgen);

  if (gw == 0) {
    float m = w1024;
#pragma unroll
    for (int t = 0; t < 16; ++t) m = fmaxf(m, vv[t]);
#pragma unroll
    for (int off = 32; off > 0; off >>= 1) m = fmaxf(m, __shfl_xor(m, off));
    float s = 0.f;
#pragma unroll
    for (int t = 0; t < 16; ++t) s += __expf(vv[t] - m);
#pragma unroll
    for (int off = 32; off > 0; off >>= 1) s += __shfl_xor(s, off);
    s += __expf(w1024 - m);
    if (lane == 0)
      slot_store(out + 1024, NORMC + LOGN - (alpha + m + logf(s)), wgen);
  }
}

__global__ __launch_bounds__(TPB) void sink_persist(const f16* __restrict__ Zh,
                                                    const f16* __restrict__ Zth,
                                                    u64* __restrict__ uS,
                                                    u64* __restrict__ vS,
                                                    const float* __restrict__ alpha_p) {
  __shared__ float lds[ZLD];
  const int tid = threadIdx.x;
  const int lane = tid & 63;
  const int gw = blockIdx.x * 4 + (tid >> 6);
  const float alpha = *alpha_p;

  f16x8 zr[4][2], zt[4][2];
#pragma unroll
  for (int r = 0; r < 4; ++r) {
    const long row = 4 * gw + r;
    const f16* zp = Zh + row * ZLD;
    const f16* ztp = Zth + row * ZLD;
#pragma unroll
    for (int hh = 0; hh < 2; ++hh)
#pragma unroll
      for (int j = 0; j < 8; ++j) {
        zr[r][hh][j] = zp[lane + 64 * (8 * hh + j)];
        zt[r][hh][j] = ztp[lane + 64 * (8 * hh + j)];
      }
  }

  unsigned gen = 0;
#pragma unroll 1
  for (int it = 0; it < 100; ++it) {
    sink_half(zr, vS, uS, gen, tid, gw, lane, alpha, lds);  ++gen;
    sink_half(zt, uS, vS, gen, tid, gw, lane, alpha, lds);  ++gen;
  }
}

__global__ __launch_bounds__(TPB) void assemble(const float* __restrict__ Z,
                                                const u64* __restrict__ uS,
                                                const u64* __restrict__ vS,
                                                float* __restrict__ out) {
  int idx = blockIdx.x * TPB + threadIdx.x;
  if (idx < 1025 * 1025) {
    int i = idx / 1025;
    int j = idx - i * 1025;
    out[idx] = Z[(long)i * ZLD + j] + slot_val(uS[i]) + slot_val(vS[j]) + LOG_MN;
  }
}

// ---------------------------------------------------------------------------
// Host orchestration
// ---------------------------------------------------------------------------
static inline GBH mkgb(const void* A, const void* B, void* C,
                       const float* bias = nullptr, const void* B2 = nullptr,
                       const float* res = nullptr,
                       const float* mu = nullptr, const float* rs = nullptr,
                       int coff = 0, void* o2a = nullptr, void* o2b = nullptr) {
  GBH g; g.A = A; g.B = B; g.B2 = B2; g.C = C; g.bias = bias; g.res = res;
  g.mu = mu; g.rs = rs; g.o2a = o2a; g.o2b = o2b; g.coff = coff; g.pad = 0;
  return g;
}

extern "C" void kernel_launch(void* const* d_in, const int* in_sizes, int n_in,
                              void* d_out, int out_size, void* d_ws, size_t ws_size,
                              hipStream_t stream) {
  const float* kp0     = (const float*)d_in[0];
  const float* kp1     = (const float*)d_in[1];
  const float* desc0   = (const float*)d_in[2];
  const float* desc1   = (const float*)d_in[3];
  const float* sc0     = (const float*)d_in[4];
  const float* sc1     = (const float*)d_in[5];
  const float* kw[4]   = {(const float*)d_in[6], (const float*)d_in[8],
                          (const float*)d_in[10], (const float*)d_in[12]};
  const float* kb[4]   = {(const float*)d_in[7], (const float*)d_in[9],
                          (const float*)d_in[11], (const float*)d_in[13]};
  const float* proj_w  = (const float*)d_in[14];
  const float* proj_b  = (const float*)d_in[15];
  const float* merge_w = (const float*)d_in[16];
  const float* merge_b = (const float*)d_in[17];
  const float* mlp_w0  = (const float*)d_in[18];
  const float* mlp_b0  = (const float*)d_in[19];
  const float* mlp_w1  = (const float*)d_in[20];
  const float* mlp_b1  = (const float*)d_in[21];
  const float* final_w = (const float*)d_in[22];
  const float* final_b = (const float*)d_in[23];
  const float* alpha_p = (const float*)d_in[24];

  float* p = (float*)d_ws;
  float* dA  = p; p += 524288;
  float* dB  = p; p += 524288;
  float* h0  = p; p += 8192;
  float* hb1 = p; p += 262144;
  float* hb2 = p; p += 131072;
  float* Mrw = p; p += 8192;
  float* Inv = p; p += 8192;
  float* Zb  = p; p += 1053700;
  float* WfB = p; p += 2359296;       // 18 x 512 x 256 fused W0b*Mw
  float* bfB = p; p += 9216;          // 18 x 512 fused bias
  float* SS1 = p; p += 18432;         // 18 x 1024 row sums
  float* SS2 = p; p += 18432;         // 18 x 1024 row sumsq
  u64* uS = (u64*)p; p += 2056;
  u64* vS = (u64*)p; p += 2056;
  f16* qkvh = (f16*)p; p += 786432;   // 6 x 256 x 1024 f16
  f16* Sh   = (f16*)p; p += 4194304;  // 8 x 1024 x 1024 f16
  f16* oAh  = (f16*)p; p += 262144;   // 2 x 1024 x 256 f16
  f16* oBh  = (f16*)p; p += 262144;
  f16* tbh  = (f16*)p; p += 524288;   // 2 x 512 x 1024 f16
  f16* mdbh = (f16*)p; p += 262144;   // 2 x 256 x 1024 f16
  f16* Zh   = (f16*)p; p += 526852;
  f16* Zth  = (f16*)p; p += 526852;
  size_t need_bytes = (size_t)(p - (float*)d_ws) * sizeof(float);
  if (ws_size < need_bytes) return;

  const long DSTR = 262144;

  // ---- weight pre-fusion (independent of activations) ----
  zero_buf<<<144, TPB, 0, stream>>>(SS1, 36864);   // zeroes SS1 and SS2 (contiguous)
  {
    GBN gb{};
    for (int l = 0; l < 18; ++l)
      gb.g[l] = mkgb(mlp_w0 + (size_t)l * 262144 + 256, merge_w + (size_t)l * 65536,
                     WfB + (size_t)l * 131072);
    gemmh<64, 64, 0, 0, 0><<<dim3(4, 8, 18), TPB, 0, stream>>>(
        gb, 256, 512, 256, 256, 1.f, 0);
  }
  bf_prep<<<36, TPB, 0, stream>>>(mlp_w0, mlp_b0, merge_b, bfB);

  // ---- keypoint encoder ----
  build_h0<<<dim3(4, 2), TPB, 0, stream>>>(kp0, kp1, sc0, sc1, h0);
  chanconv<true, false><<<dim3(32, 2),  TPB, 0, stream>>>(kw[0], kb[0], h0,  4096,   nullptr, nullptr, hb1, 32768,  4);
  chanconv<true, false><<<dim3(64, 2),  TPB, 0, stream>>>(kw[1], kb[1], hb1, 32768,  nullptr, nullptr, hb2, 65536,  32);
  chanconv<true, false><<<dim3(128, 2), TPB, 0, stream>>>(kw[2], kb[2], hb2, 65536,  nullptr, nullptr, hb1, 131072, 64);
  chanconv<false, true><<<dim3(256, 2), TPB, 0, stream>>>(kw[3], kb[3], hb1, 131072, desc0,   desc1,   dA,  DSTR,   128);

  // ---- GNN layers ----
  float* dc = dA;
  float* dn = dB;
  for (int i = 0; i < 18; ++i) {
    bool cross = (i & 1) != 0;
    const float* xs[2] = {dc, dc + DSTR};
    const float* ss2[2] = {cross ? xs[1] : xs[0], cross ? xs[0] : xs[1]};

    // K1: q/k/v projections -> qkvh f16
    {
      GBN gb{};
      for (int im = 0; im < 2; ++im)
        for (int pp = 0; pp < 3; ++pp)
          gb.g[im * 3 + pp] = mkgb(proj_w + (size_t)(i * 3 + pp) * 65536,
                                   (pp == 0 ? xs[im] : ss2[im]),
                                   qkvh + (size_t)(im * 3 + pp) * DSTR,
                                   proj_b + (size_t)(i * 3 + pp) * 256);
      gemmh<32, 128, 0, 0, F_CD16><<<dim3(8, 8, 6), TPB, 0, stream>>>(
          gb, 256, 256, 1024, 1024, 1.f, 0);
    }
    // K2: S = q^T k / 8 -> Sh f16
    {
      GBN gb{};
      for (int im = 0; im < 2; ++im)
        for (int h = 0; h < 4; ++h)
          gb.g[im * 4 + h] = mkgb(qkvh + (size_t)(im * 3 + 0) * DSTR + h * 1024,
                                  qkvh + (size_t)(im * 3 + 1) * DSTR + h * 1024,
                                  Sh + (size_t)(im * 4 + h) * 1048576);
      gemmh<64, 128, 1, 1, F_CD16><<<dim3(8, 16, 8), TPB, 0, stream>>>(
          gb, 64, 4096, 4096, 1024, 0.125f, 0);
    }
    // K3: per-row softmax stats
    rowlse_h<<<2048, TPB, 0, stream>>>(Sh, Mrw, Inv);
    // K4T: oT[pos][4*d+h] = sum_kv P * v ; K split in halves -> oAh/oBh
    {
      GBN gb{};
      for (int kh = 0; kh < 2; ++kh)
        for (int imh = 0; imh < 8; ++imh) {
          int im = imh >> 2, h = imh & 3;
          gb.g[kh * 8 + imh] = mkgb(Sh + (size_t)imh * 1048576 + kh * 512,
                                    qkvh + (size_t)(im * 3 + 2) * DSTR + h * 1024 + kh * 512,
                                    (kh ? oBh : oAh) + (size_t)im * 262144,
                                    nullptr, nullptr, nullptr,
                                    Mrw + imh * 1024, Inv + imh * 1024, h);
        }
      gemmh<64, 64, 2, 2, F_CD16 | F_CSCAT><<<dim3(1, 16, 16), TPB, 0, stream>>>(
          gb, 512, 1024, 4096, 256, 1.f, 0);
    }
    // K6': tb = [W0a|Wf] x [x; oA+oB] + bf ; epilogue accumulates row stats
    {
      GBN gb{};
      for (int im = 0; im < 2; ++im)
        gb.g[im] = mkgb(mlp_w0 + (size_t)i * 262144, xs[im],
                        tbh + (size_t)im * 524288, bfB + (size_t)i * 512,
                        oAh + (size_t)im * 262144, nullptr,
                        SS1 + (size_t)i * 1024 + im * 512,
                        SS2 + (size_t)i * 1024 + im * 512,
                        0, WfB + (size_t)i * 131072, oBh + (size_t)im * 262144);
      gemmh<64, 64, 0, 0, F_CD16 | F_ACONCAT | F_BMIX | F_STATS>
          <<<dim3(16, 8, 2), TPB, 0, stream>>>(
          gb, 512, 512, 1024, 1024, 1.f, 256);
    }
    // K8: mlp1 with inorm+relu from raw sums, fp32 residual -> dn
    {
      GBN gb{};
      for (int im = 0; im < 2; ++im)
        gb.g[im] = mkgb(mlp_w1 + (size_t)i * 131072, tbh + (size_t)im * 524288,
                        dn + (size_t)im * DSTR, mlp_b1 + (size_t)i * 256,
                        nullptr, xs[im],
                        SS1 + (size_t)i * 1024 + im * 512,
                        SS2 + (size_t)i * 1024 + im * 512);
      gemmh<32, 64, 0, 1, F_BNORM2 | F_RES><<<dim3(16, 8, 2), TPB, 0, stream>>>(
          gb, 512, 512, 1024, 1024, 1.f, 0);
    }
    float* tmp = dc; dc = dn; dn = tmp;
  }

  // ---- final projection -> mdbh f16 ----
  {
    GBN gb{};
    for (int im = 0; im < 2; ++im)
      gb.g[im] = mkgb(final_w, dc + (size_t)im * DSTR, mdbh + (size_t)im * 262144,
                      final_b);
    gemmh<32, 64, 0, 0, F_CD16><<<dim3(16, 8, 2), TPB, 0, stream>>>(
        gb, 256, 256, 1024, 1024, 1.f, 0);
  }
  // ---- scores -> Zb fp32 + Zh/Zth f16 ----
  {
    GBN gb{};
    gb.g[0] = mkgb(mdbh, mdbh + 262144, Zb, nullptr, nullptr, nullptr,
                   nullptr, nullptr, 0, Zh, Zth);
    gemmh<64, 64, 1, 1, F_OUT2><<<dim3(16, 16, 1), TPB, 0, stream>>>(
        gb, 256, 1024, 1024, ZLD, 0.0625f, 0);
  }
  fill_bins<<<5, TPB, 0, stream>>>(Zb, alpha_p, uS, vS);

  // ---- Sinkhorn: persistent kernel, barrier-free tagged dataflow ----
  sink_persist<<<SINKB, TPB, 0, stream>>>(Zh, Zth, uS, vS, alpha_p);

  // ---- output ----
  assemble<<<4105, TPB, 0, stream>>>(Zb, uS, vS, (float*)d_out);
}

// Round 11
// 2133.626 us; speedup vs baseline: 1.1351x; 1.0611x over previous
//
#include <hip/hip_runtime.h>
#include <cstddef>

#define TPB 256

typedef _Float16 f16;
typedef _Float16 f16x4 __attribute__((ext_vector_type(4)));
typedef _Float16 f16x8 __attribute__((ext_vector_type(8)));
typedef float f32x4 __attribute__((ext_vector_type(4)));
typedef unsigned long long u64;

// ---------------------------------------------------------------------------
// block reduction (for chanconv)
// ---------------------------------------------------------------------------
__device__ __forceinline__ float block_sum(float v, float* red) {
  int tid = threadIdx.x;
  red[tid] = v; __syncthreads();
#pragma unroll
  for (int off = 128; off > 0; off >>= 1) {
    if (tid < off) red[tid] += red[tid + off];
    __syncthreads();
  }
  float r = red[0];
  __syncthreads();
  return r;
}

// ---------------------------------------------------------------------------
// h0 build: h0[im][4][1024]
// ---------------------------------------------------------------------------
__global__ __launch_bounds__(TPB) void build_h0(const float* __restrict__ kp0,
                                                const float* __restrict__ kp1,
                                                const float* __restrict__ sc0,
                                                const float* __restrict__ sc1,
                                                float* __restrict__ h0) {
  int n = blockIdx.x * TPB + threadIdx.x;
  int im = blockIdx.y;
  const float* kp = im ? kp1 : kp0;
  const float* sc = im ? sc1 : sc0;
  float* h = h0 + (size_t)im * 4096;
  h[n]        = kp[n * 3 + 0];
  h[1024 + n] = kp[n * 3 + 1];
  h[2048 + n] = kp[n * 3 + 2];
  h[3072 + n] = sc[n];
}

// ---------------------------------------------------------------------------
// kenc conv layer (fp32, small)
// ---------------------------------------------------------------------------
template<bool NORMRELU, bool RESID>
__global__ __launch_bounds__(TPB) void chanconv(const float* __restrict__ W,
                                                const float* __restrict__ bias,
                                                const float* __restrict__ in, long instride,
                                                const float* res0, const float* res1,
                                                float* __restrict__ out, long outstride, int C) {
  int o = blockIdx.x, im = blockIdx.y, tid = threadIdx.x;
  const float* inp = in + (long)im * instride;
  __shared__ float Ws[128];
  __shared__ float red[TPB];
  for (int c = tid; c < C; c += TPB) Ws[c] = W[(long)o * C + c];
  __syncthreads();
  float b = bias[o];
  float4 acc = {b, b, b, b};
  for (int c = 0; c < C; ++c) {
    float w = Ws[c];
    float4 v = *(const float4*)(inp + (long)c * 1024 + tid * 4);
    acc.x += w * v.x; acc.y += w * v.y; acc.z += w * v.z; acc.w += w * v.w;
  }
  float* orow = out + (long)im * outstride + (long)o * 1024;
  if (NORMRELU) {
    float s = acc.x + acc.y + acc.z + acc.w;
    float mean = block_sum(s, red) * (1.f / 1024.f);
    float dx = acc.x - mean, dy = acc.y - mean, dz = acc.z - mean, dw = acc.w - mean;
    float var = block_sum(dx * dx + dy * dy + dz * dz + dw * dw, red) * (1.f / 1024.f);
    float rstd = rsqrtf(var + 1e-5f);
    float4 o4 = {fmaxf(dx * rstd, 0.f), fmaxf(dy * rstd, 0.f),
                 fmaxf(dz * rstd, 0.f), fmaxf(dw * rstd, 0.f)};
    *(float4*)(orow + tid * 4) = o4;
  } else {
    if (RESID) {
      const float* res = im ? res1 : res0;
      float4 r = *(const float4*)(res + (long)o * 1024 + tid * 4);
      acc.x += r.x; acc.y += r.y; acc.z += r.z; acc.w += r.w;
    }
    *(float4*)(orow + tid * 4) = acc;
  }
}

// ---------------------------------------------------------------------------
// fp16-MFMA batched GEMM. Block BMxBN, 4 waves, wave (BM==64? 2x2 : 1x4).
// MFMA v_mfma_f32_16x16x16_f16; A-frag lane l: row=l&15, k=4*(l>>4)+j;
// B-frag: col=l&15, same k; D: col=l&15, row=4*(l>>4)+reg.
//   ASRC 0: fp32 [m][k] (+F_ACONCAT: k>=ksplit from o2a fp32 ld=256)
//   ASRC 1: f16 [k][m]
//   ASRC 2: f16 [m][k] + softmax exp (mu=M, rs=inv)
//   BSRC 0: fp32 [k][n] (+F_BMIX: k>=ksplit -> f16 (B2+o2b)[n][k'] ld=256)
//   BSRC 1: f16 [k][n] (+F_BNORM mu/rs | +F_BNORM2 from raw sums)
//   BSRC 2: f16 [n][k] (+F_BADD add B2)
// F_STATS: epilogue accumulates per-row sum/sumsq into g.mu/g.rs (atomicAdd).
// ---------------------------------------------------------------------------
struct GBH {
  const void* A; const void* B; const void* B2; void* C;
  const float* bias; const float* res; const float* mu; const float* rs;
  void* o2a; void* o2b; int coff; int pad;
};
struct GBN { GBH g[18]; };

#define F_BNORM   1
#define F_BCONCAT 2
#define F_BADD    4
#define F_CD16    8
#define F_RES     16
#define F_OUT2    32
#define F_CSCAT   64
#define F_BNORM2  128
#define F_ACONCAT 256
#define F_BMIX    512
#define F_STATS   1024

template<int BM, int BN, int ASRC, int BSRC, int FLAGS>
__global__ __launch_bounds__(TPB) void gemmh(GBN gbs, int K, int lda, int ldb,
                                             int ldc, float alpha, int ksplit) {
  constexpr int WM = BM / 32;          // 2 or 1
  constexpr int NWN = 4 / WM;          // waves along N: 2 or 4
  constexpr int WN = BN / NWN;
  constexpr int NFR = WN / 16;
  GBH g = gbs.g[blockIdx.z];
  const int tid = threadIdx.x;
  const int lane = tid & 63, wid = tid >> 6;
  const int wm = wid / NWN, wn = wid % NWN;
  const int m0 = blockIdx.y * BM, n0 = blockIdx.x * BN;
  __shared__ f16 As[BM][36];
  __shared__ f16 Bs[BN][36];
  f32x4 acc[2][NFR];
#pragma unroll
  for (int i = 0; i < 2; ++i)
#pragma unroll
    for (int j = 0; j < NFR; ++j) acc[i][j] = (f32x4){0.f, 0.f, 0.f, 0.f};

  for (int k0 = 0; k0 < K; k0 += 32) {
    // ---- stage A ----
    if constexpr (ASRC == 0) {
      if constexpr (BM == 64) {
        const int m = tid >> 2, k4 = (tid & 3) * 8;
        const float* ap;
        if constexpr ((FLAGS & F_ACONCAT) != 0) {
          if (k0 >= ksplit)
            ap = (const float*)g.o2a + (long)(m0 + m) * 256 + (k0 - ksplit) + k4;
          else
            ap = (const float*)g.A + (long)(m0 + m) * lda + k0 + k4;
        } else {
          ap = (const float*)g.A + (long)(m0 + m) * lda + k0 + k4;
        }
        float4 u0 = *(const float4*)ap, u1 = *(const float4*)(ap + 4);
        f16x4 h0 = {(f16)u0.x, (f16)u0.y, (f16)u0.z, (f16)u0.w};
        f16x4 h1 = {(f16)u1.x, (f16)u1.y, (f16)u1.z, (f16)u1.w};
        *(f16x4*)&As[m][k4] = h0;
        *(f16x4*)&As[m][k4 + 4] = h1;
      } else {
        const int m = tid >> 3, k4 = (tid & 7) * 4;
        const float* ap = (const float*)g.A + (long)(m0 + m) * lda + k0 + k4;
        float4 u0 = *(const float4*)ap;
        f16x4 h0 = {(f16)u0.x, (f16)u0.y, (f16)u0.z, (f16)u0.w};
        *(f16x4*)&As[m][k4] = h0;
      }
    } else if constexpr (ASRC == 1) {
      const int k = tid >> 3, mg = (tid & 7) * 8;
      const f16* ap = (const f16*)g.A + (long)(k0 + k) * lda + m0 + mg;
      f16x8 h = *(const f16x8*)ap;
#pragma unroll
      for (int j = 0; j < 8; ++j) As[mg + j][k] = h[j];
    } else {
      if constexpr (BM == 64) {
        const int m = tid >> 2, k4 = (tid & 3) * 8;
        const f16* ap = (const f16*)g.A + (long)(m0 + m) * lda + k0 + k4;
        f16x8 h = *(const f16x8*)ap;
        const float M = g.mu[m0 + m], Iv = g.rs[m0 + m];
        f16x4 h0, h1;
#pragma unroll
        for (int j = 0; j < 4; ++j) h0[j] = (f16)(__expf((float)h[j] - M) * Iv);
#pragma unroll
        for (int j = 0; j < 4; ++j) h1[j] = (f16)(__expf((float)h[j + 4] - M) * Iv);
        *(f16x4*)&As[m][k4] = h0;
        *(f16x4*)&As[m][k4 + 4] = h1;
      } else {
        const int m = tid >> 3, k4 = (tid & 7) * 4;
        const f16* ap = (const f16*)g.A + (long)(m0 + m) * lda + k0 + k4;
        f16x4 h = *(const f16x4*)ap;
        const float M = g.mu[m0 + m], Iv = g.rs[m0 + m];
        f16x4 h0;
#pragma unroll
        for (int j = 0; j < 4; ++j) h0[j] = (f16)(__expf((float)h[j] - M) * Iv);
        *(f16x4*)&As[m][k4] = h0;
      }
    }
    // ---- stage B ----
#pragma unroll
    for (int r = 0; r < BN / 64; ++r) {
      if constexpr (BSRC == 0) {
        bool f16path = false;
        if constexpr ((FLAGS & F_BMIX) != 0) f16path = (k0 >= ksplit);
        if (f16path) {
          const int n = (tid >> 2) + r * 64, k4b = (tid & 3) * 8;
          const long off = (long)(n0 + n) * 256 + (k0 - ksplit) + k4b;
          f16x8 h = *(const f16x8*)((const f16*)g.B2 + off)
                  + *(const f16x8*)((const f16*)g.o2b + off);
          f16x4 h0 = {h[0], h[1], h[2], h[3]};
          f16x4 h1 = {h[4], h[5], h[6], h[7]};
          *(f16x4*)&Bs[n][k4b] = h0;
          *(f16x4*)&Bs[n][k4b + 4] = h1;
        } else {
          const int k = tid >> 3, ng = (tid & 7) * 8 + r * 64;
          const int kg = k0 + k;
          const float* bp;
          if constexpr ((FLAGS & F_BCONCAT) != 0)
            bp = (kg < ksplit) ? ((const float*)g.B + (long)kg * ldb)
                               : ((const float*)g.B2 + (long)(kg - ksplit) * ldb);
          else
            bp = (const float*)g.B + (long)kg * ldb;
          float4 u0 = *(const float4*)(bp + n0 + ng);
          float4 u1 = *(const float4*)(bp + n0 + ng + 4);
          Bs[ng + 0][k] = (f16)u0.x; Bs[ng + 1][k] = (f16)u0.y;
          Bs[ng + 2][k] = (f16)u0.z; Bs[ng + 3][k] = (f16)u0.w;
          Bs[ng + 4][k] = (f16)u1.x; Bs[ng + 5][k] = (f16)u1.y;
          Bs[ng + 6][k] = (f16)u1.z; Bs[ng + 7][k] = (f16)u1.w;
        }
      } else if constexpr (BSRC == 1) {
        const int k = tid >> 3, ng = (tid & 7) * 8 + r * 64;
        const int kg = k0 + k;
        f16x8 h = *(const f16x8*)((const f16*)g.B + (long)kg * ldb + n0 + ng);
        if constexpr ((FLAGS & (F_BNORM | F_BNORM2)) != 0) {
          float mean, rstd;
          if constexpr ((FLAGS & F_BNORM2) != 0) {
            float s1 = g.mu[kg], s2 = g.rs[kg];
            mean = s1 * (1.f / 1024.f);
            rstd = rsqrtf(fmaxf(s2 * (1.f / 1024.f) - mean * mean, 0.f) + 1e-5f);
          } else {
            mean = g.mu[kg]; rstd = g.rs[kg];
          }
#pragma unroll
          for (int j = 0; j < 8; ++j)
            h[j] = (f16)fmaxf(((float)h[j] - mean) * rstd, 0.f);
        }
#pragma unroll
        for (int j = 0; j < 8; ++j) Bs[ng + j][k] = h[j];
      } else {
        const int n = (tid >> 2) + r * 64, k4 = (tid & 3) * 8;
        const f16* bp = (const f16*)g.B + (long)(n0 + n) * ldb + k0 + k4;
        f16x8 h = *(const f16x8*)bp;
        if constexpr ((FLAGS & F_BADD) != 0) {
          f16x8 h2 = *(const f16x8*)((const f16*)g.B2 + (long)(n0 + n) * ldb + k0 + k4);
          h = h + h2;
        }
        f16x4 h0 = {h[0], h[1], h[2], h[3]};
        f16x4 h1 = {h[4], h[5], h[6], h[7]};
        *(f16x4*)&Bs[n][k4] = h0;
        *(f16x4*)&Bs[n][k4 + 4] = h1;
      }
    }
    __syncthreads();
    // ---- MFMA ----
#pragma unroll
    for (int ks = 0; ks < 2; ++ks) {
      const int kof = ks * 16 + ((lane >> 4) << 2);
      f16x4 a[2], b[NFR];
      a[0] = *(const f16x4*)&As[wm * 32 + (lane & 15)][kof];
      a[1] = *(const f16x4*)&As[wm * 32 + 16 + (lane & 15)][kof];
#pragma unroll
      for (int fn = 0; fn < NFR; ++fn)
        b[fn] = *(const f16x4*)&Bs[wn * WN + fn * 16 + (lane & 15)][kof];
#pragma unroll
      for (int fm = 0; fm < 2; ++fm)
#pragma unroll
        for (int fn = 0; fn < NFR; ++fn)
          acc[fm][fn] = __builtin_amdgcn_mfma_f32_16x16x16f16(a[fm], b[fn], acc[fm][fn], 0, 0, 0);
    }
    __syncthreads();
  }

  // ---- epilogue ----
  const int r0 = (lane >> 4) << 2, cn = lane & 15;
#pragma unroll
  for (int fm = 0; fm < 2; ++fm) {
#pragma unroll
    for (int r = 0; r < 4; ++r) {
      const int m = m0 + wm * 32 + fm * 16 + r0 + r;
      const float bi = g.bias ? g.bias[m] : 0.f;
      float s1 = 0.f, s2 = 0.f;
#pragma unroll
      for (int fn = 0; fn < NFR; ++fn) {
        const int n = n0 + wn * WN + fn * 16 + cn;
        float v = acc[fm][fn][r] * alpha + bi;
        if constexpr ((FLAGS & F_RES) != 0) v += g.res[(long)m * ldc + n];
        if constexpr ((FLAGS & F_OUT2) != 0) {
          ((float*)g.C)[(long)m * 1028 + n] = v;
          ((f16*)g.o2a)[(long)m * 1028 + n] = (f16)v;
          ((f16*)g.o2b)[(long)n * 1028 + m] = (f16)v;
        } else if constexpr ((FLAGS & F_CSCAT) != 0) {
          ((f16*)g.C)[(long)m * ldc + g.coff + 4 * n] = (f16)v;
        } else if constexpr ((FLAGS & F_CD16) != 0) {
          ((f16*)g.C)[(long)m * ldc + n] = (f16)v;
        } else {
          ((float*)g.C)[(long)m * ldc + n] = v;
        }
        if constexpr ((FLAGS & F_STATS) != 0) { s1 += v; s2 += v * v; }
      }
      if constexpr ((FLAGS & F_STATS) != 0) {
#pragma unroll
        for (int off = 1; off < 16; off <<= 1) {
          s1 += __shfl_xor(s1, off);
          s2 += __shfl_xor(s2, off);
        }
        if ((lane & 15) == 0) {
          atomicAdd((float*)g.mu + m, s1);
          atomicAdd((float*)g.rs + m, s2);
        }
      }
    }
  }
}

// ---------------------------------------------------------------------------
// rowlse over f16 S rows (1024 wide): Mrow, Inv = 1/sum(exp(x-M)). Wave/row.
// ---------------------------------------------------------------------------
__global__ __launch_bounds__(TPB) void rowlse_h(const f16* __restrict__ S,
                                                float* __restrict__ Mrow,
                                                float* __restrict__ Inv) {
  int row = blockIdx.x * 4 + (threadIdx.x >> 6);
  int lane = threadIdx.x & 63;
  const f16x8* p = (const f16x8*)(S + (long)row * 1024);
  f16x8 v0 = p[lane], v1 = p[lane + 64];
  float m = -1e30f;
#pragma unroll
  for (int j = 0; j < 8; ++j)
    m = fmaxf(m, fmaxf((float)v0[j], (float)v1[j]));
#pragma unroll
  for (int off = 32; off > 0; off >>= 1) m = fmaxf(m, __shfl_xor(m, off));
  float s = 0.f;
#pragma unroll
  for (int j = 0; j < 8; ++j)
    s += __expf((float)v0[j] - m) + __expf((float)v1[j] - m);
#pragma unroll
  for (int off = 32; off > 0; off >>= 1) s += __shfl_xor(s, off);
  if (lane == 0) { Mrow[row] = m; Inv[row] = 1.f / s; }
}

// ---------------------------------------------------------------------------
// weight pre-fusion helpers
// ---------------------------------------------------------------------------
__global__ __launch_bounds__(TPB) void zero_buf(float* __restrict__ p, int n) {
  int i = blockIdx.x * TPB + threadIdx.x;
  if (i < n) p[i] = 0.f;
}

// bf[l][m] = mlp_b0[l][m] + dot(mlp_w0[l][m][256:512], merge_b[l])
__global__ __launch_bounds__(TPB) void bf_prep(const float* __restrict__ mlp_w0,
                                               const float* __restrict__ mlp_b0,
                                               const float* __restrict__ merge_b,
                                               float* __restrict__ bfB) {
  int idx = blockIdx.x * TPB + threadIdx.x;   // 0..9215
  int l = idx >> 9, m = idx & 511;
  const float* wrow = mlp_w0 + (size_t)l * 262144 + (size_t)m * 512 + 256;
  const float* mb = merge_b + (size_t)l * 256;
  float s = mlp_b0[(size_t)l * 512 + m];
  for (int j = 0; j < 256; ++j) s += wrow[j] * mb[j];
  bfB[idx] = s;
}

// ---------------------------------------------------------------------------
// Sinkhorn — persistent, Z in registers, barrier-free generation-tagged slots
// + block-consolidated consume + PARALLEL 4-way poll + double-buffered LDS.
// ---------------------------------------------------------------------------
#define NORMC  (-7.62461899f)   /* -log(2048) */
#define LOGN   (6.93147181f)    /* log(1024)  */
#define LOG_MN (7.62461899f)    /* log(2048)  */
#define ZLD    1028
#define SINKB  64

__device__ __forceinline__ u64 llc_load64(const u64* p) {
  return __hip_atomic_load(p, __ATOMIC_RELAXED, __HIP_MEMORY_SCOPE_AGENT);
}
__device__ __forceinline__ void slot_store(u64* p, float v, unsigned gen) {
  union { float f; unsigned u; } c; c.f = v;
  u64 x = ((u64)gen << 32) | (u64)c.u;
  __hip_atomic_store(p, x, __ATOMIC_RELAXED, __HIP_MEMORY_SCOPE_AGENT);
}
__device__ __forceinline__ float slot_val(u64 x) {
  union { unsigned u; float f; } c; c.u = (unsigned)x;
  return c.f;
}

__global__ __launch_bounds__(TPB) void fill_bins(float* __restrict__ Z,
                                                 const float* __restrict__ alpha_p,
                                                 u64* __restrict__ uS,
                                                 u64* __restrict__ vS) {
  float a = *alpha_p;
  int t = blockIdx.x * TPB + threadIdx.x;
  if (t <= 1024) {
    Z[(long)t * ZLD + 1024] = a;
    Z[(long)1024 * ZLD + t] = a;
    slot_store(uS + t, 0.f, 0u);
    slot_store(vS + t, 0.f, 0u);
  }
}

__device__ __forceinline__ void sink_half(const f16x8 zreg[4][2],
                                          const u64* __restrict__ w,
                                          u64* __restrict__ out,
                                          unsigned rgen, int tid, int gw, int lane,
                                          float alpha, float* __restrict__ lds) {
  // parallel poll: all 4 (+1) slot loads in flight per retry round
  u64 x0, x1, x2, x3, xb = 0;
  bool ok = false;
  while (!ok) {
    x0 = llc_load64(w + tid);
    x1 = llc_load64(w + tid + 256);
    x2 = llc_load64(w + tid + 512);
    x3 = llc_load64(w + tid + 768);
    ok = ((unsigned)(x0 >> 32) == rgen) & ((unsigned)(x1 >> 32) == rgen)
       & ((unsigned)(x2 >> 32) == rgen) & ((unsigned)(x3 >> 32) == rgen);
    if (tid == 0) {
      xb = llc_load64(w + 1024);
      ok = ok & ((unsigned)(xb >> 32) == rgen);
    }
  }
  lds[tid]       = slot_val(x0);
  lds[tid + 256] = slot_val(x1);
  lds[tid + 512] = slot_val(x2);
  lds[tid + 768] = slot_val(x3);
  if (tid == 0) lds[1024] = slot_val(xb);
  __syncthreads();

  float vv[16];
#pragma unroll
  for (int t = 0; t < 16; ++t) vv[t] = lds[lane + 64 * t];
  const float w1024 = lds[1024];
  const float binv = alpha + w1024;
  const unsigned wgen = rgen + 1;

  float res[4];
#pragma unroll
  for (int r = 0; r < 4; ++r) {
    float val[16];
    float m = binv;
#pragma unroll
    for (int t = 0; t < 16; ++t) {
      val[t] = (float)zreg[r][t >> 3][t & 7] + vv[t];
      m = fmaxf(m, val[t]);
    }
#pragma unroll
    for (int off = 32; off > 0; off >>= 1) m = fmaxf(m, __shfl_xor(m, off));
    float s = 0.f;
#pragma unroll
    for (int t = 0; t < 16; ++t) s += __expf(val[t] - m);
#pragma unroll
    for (int off = 32; off > 0; off >>= 1) s += __shfl_xor(s, off);
    s += __expf(binv - m);
    res[r] = NORMC - (m + logf(s));
  }
  float myv = (lane == 0) ? res[0] : (lane == 1) ? res[1]
            : (lane == 2) ? res[2] : res[3];
  if (lane < 4) slot_store(out + 4 * gw + lane, myv, wgen);

  if (gw == 0) {
    float m = w1024;
#pragma unroll
    for (int t = 0; t < 16; ++t) m = fmaxf(m, vv[t]);
#pragma unroll
    for (int off = 32; off > 0; off >>= 1) m = fmaxf(m, __shfl_xor(m, off));
    float s = 0.f;
#pragma unroll
    for (int t = 0; t < 16; ++t) s += __expf(vv[t] - m);
#pragma unroll
    for (int off = 32; off > 0; off >>= 1) s += __shfl_xor(s, off);
    s += __expf(w1024 - m);
    if (lane == 0)
      slot_store(out + 1024, NORMC + LOGN - (alpha + m + logf(s)), wgen);
  }
}

__global__ __launch_bounds__(TPB) void sink_persist(const f16* __restrict__ Zh,
                                                    const f16* __restrict__ Zth,
                                                    u64* __restrict__ uS,
                                                    u64* __restrict__ vS,
                                                    const float* __restrict__ alpha_p) {
  __shared__ float lds0[ZLD];
  __shared__ float lds1[ZLD];
  const int tid = threadIdx.x;
  const int lane = tid & 63;
  const int gw = blockIdx.x * 4 + (tid >> 6);
  const float alpha = *alpha_p;

  f16x8 zr[4][2], zt[4][2];
#pragma unroll
  for (int r = 0; r < 4; ++r) {
    const long row = 4 * gw + r;
    const f16* zp = Zh + row * ZLD;
    const f16* ztp = Zth + row * ZLD;
#pragma unroll
    for (int hh = 0; hh < 2; ++hh)
#pragma unroll
      for (int j = 0; j < 8; ++j) {
        zr[r][hh][j] = zp[lane + 64 * (8 * hh + j)];
        zt[r][hh][j] = ztp[lane + 64 * (8 * hh + j)];
      }
  }

  unsigned gen = 0;
#pragma unroll 1
  for (int it = 0; it < 100; ++it) {
    sink_half(zr, vS, uS, gen, tid, gw, lane, alpha, lds0);  ++gen;
    sink_half(zt, uS, vS, gen, tid, gw, lane, alpha, lds1);  ++gen;
  }
}

__global__ __launch_bounds__(TPB) void assemble(const float* __restrict__ Z,
                                                const u64* __restrict__ uS,
                                                const u64* __restrict__ vS,
                                                float* __restrict__ out) {
  int idx = blockIdx.x * TPB + threadIdx.x;
  if (idx < 1025 * 1025) {
    int i = idx / 1025;
    int j = idx - i * 1025;
    out[idx] = Z[(long)i * ZLD + j] + slot_val(uS[i]) + slot_val(vS[j]) + LOG_MN;
  }
}

// ---------------------------------------------------------------------------
// Host orchestration
// ---------------------------------------------------------------------------
static inline GBH mkgb(const void* A, const void* B, void* C,
                       const float* bias = nullptr, const void* B2 = nullptr,
                       const float* res = nullptr,
                       const float* mu = nullptr, const float* rs = nullptr,
                       int coff = 0, void* o2a = nullptr, void* o2b = nullptr) {
  GBH g; g.A = A; g.B = B; g.B2 = B2; g.C = C; g.bias = bias; g.res = res;
  g.mu = mu; g.rs = rs; g.o2a = o2a; g.o2b = o2b; g.coff = coff; g.pad = 0;
  return g;
}

extern "C" void kernel_launch(void* const* d_in, const int* in_sizes, int n_in,
                              void* d_out, int out_size, void* d_ws, size_t ws_size,
                              hipStream_t stream) {
  const float* kp0     = (const float*)d_in[0];
  const float* kp1     = (const float*)d_in[1];
  const float* desc0   = (const float*)d_in[2];
  const float* desc1   = (const float*)d_in[3];
  const float* sc0     = (const float*)d_in[4];
  const float* sc1     = (const float*)d_in[5];
  const float* kw[4]   = {(const float*)d_in[6], (const float*)d_in[8],
                          (const float*)d_in[10], (const float*)d_in[12]};
  const float* kb[4]   = {(const float*)d_in[7], (const float*)d_in[9],
                          (const float*)d_in[11], (const float*)d_in[13]};
  const float* proj_w  = (const float*)d_in[14];
  const float* proj_b  = (const float*)d_in[15];
  const float* merge_w = (const float*)d_in[16];
  const float* merge_b = (const float*)d_in[17];
  const float* mlp_w0  = (const float*)d_in[18];
  const float* mlp_b0  = (const float*)d_in[19];
  const float* mlp_w1  = (const float*)d_in[20];
  const float* mlp_b1  = (const float*)d_in[21];
  const float* final_w = (const float*)d_in[22];
  const float* final_b = (const float*)d_in[23];
  const float* alpha_p = (const float*)d_in[24];

  float* p = (float*)d_ws;
  float* dA  = p; p += 524288;
  float* dB  = p; p += 524288;
  float* h0  = p; p += 8192;
  float* hb1 = p; p += 262144;
  float* hb2 = p; p += 131072;
  float* Mrw = p; p += 8192;
  float* Inv = p; p += 8192;
  float* Zb  = p; p += 1053700;
  float* WfB = p; p += 2359296;       // 18 x 512 x 256 fused W0b*Mw
  float* bfB = p; p += 9216;          // 18 x 512 fused bias
  float* SS1 = p; p += 18432;         // 18 x 1024 row sums
  float* SS2 = p; p += 18432;         // 18 x 1024 row sumsq
  u64* uS = (u64*)p; p += 2056;
  u64* vS = (u64*)p; p += 2056;
  f16* qkvh = (f16*)p; p += 786432;   // 6 x 256 x 1024 f16
  f16* Sh   = (f16*)p; p += 4194304;  // 8 x 1024 x 1024 f16
  f16* oAh  = (f16*)p; p += 262144;   // 2 x 1024 x 256 f16
  f16* oBh  = (f16*)p; p += 262144;
  f16* tbh  = (f16*)p; p += 524288;   // 2 x 512 x 1024 f16
  f16* mdbh = (f16*)p; p += 262144;   // 2 x 256 x 1024 f16
  f16* Zh   = (f16*)p; p += 526852;
  f16* Zth  = (f16*)p; p += 526852;
  size_t need_bytes = (size_t)(p - (float*)d_ws) * sizeof(float);
  if (ws_size < need_bytes) return;

  const long DSTR = 262144;

  // ---- weight pre-fusion (independent of activations) ----
  zero_buf<<<144, TPB, 0, stream>>>(SS1, 36864);   // zeroes SS1 and SS2 (contiguous)
  {
    GBN gb{};
    for (int l = 0; l < 18; ++l)
      gb.g[l] = mkgb(mlp_w0 + (size_t)l * 262144 + 256, merge_w + (size_t)l * 65536,
                     WfB + (size_t)l * 131072);
    gemmh<64, 64, 0, 0, 0><<<dim3(4, 8, 18), TPB, 0, stream>>>(
        gb, 256, 512, 256, 256, 1.f, 0);
  }
  bf_prep<<<36, TPB, 0, stream>>>(mlp_w0, mlp_b0, merge_b, bfB);

  // ---- keypoint encoder ----
  build_h0<<<dim3(4, 2), TPB, 0, stream>>>(kp0, kp1, sc0, sc1, h0);
  chanconv<true, false><<<dim3(32, 2),  TPB, 0, stream>>>(kw[0], kb[0], h0,  4096,   nullptr, nullptr, hb1, 32768,  4);
  chanconv<true, false><<<dim3(64, 2),  TPB, 0, stream>>>(kw[1], kb[1], hb1, 32768,  nullptr, nullptr, hb2, 65536,  32);
  chanconv<true, false><<<dim3(128, 2), TPB, 0, stream>>>(kw[2], kb[2], hb2, 65536,  nullptr, nullptr, hb1, 131072, 64);
  chanconv<false, true><<<dim3(256, 2), TPB, 0, stream>>>(kw[3], kb[3], hb1, 131072, desc0,   desc1,   dA,  DSTR,   128);

  // ---- GNN layers ----
  float* dc = dA;
  float* dn = dB;
  for (int i = 0; i < 18; ++i) {
    bool cross = (i & 1) != 0;
    const float* xs[2] = {dc, dc + DSTR};
    const float* ss2[2] = {cross ? xs[1] : xs[0], cross ? xs[0] : xs[1]};

    // K1: q/k/v projections -> qkvh f16
    {
      GBN gb{};
      for (int im = 0; im < 2; ++im)
        for (int pp = 0; pp < 3; ++pp)
          gb.g[im * 3 + pp] = mkgb(proj_w + (size_t)(i * 3 + pp) * 65536,
                                   (pp == 0 ? xs[im] : ss2[im]),
                                   qkvh + (size_t)(im * 3 + pp) * DSTR,
                                   proj_b + (size_t)(i * 3 + pp) * 256);
      gemmh<32, 128, 0, 0, F_CD16><<<dim3(8, 8, 6), TPB, 0, stream>>>(
          gb, 256, 256, 1024, 1024, 1.f, 0);
    }
    // K2: S = q^T k / 8 -> Sh f16
    {
      GBN gb{};
      for (int im = 0; im < 2; ++im)
        for (int h = 0; h < 4; ++h)
          gb.g[im * 4 + h] = mkgb(qkvh + (size_t)(im * 3 + 0) * DSTR + h * 1024,
                                  qkvh + (size_t)(im * 3 + 1) * DSTR + h * 1024,
                                  Sh + (size_t)(im * 4 + h) * 1048576);
      gemmh<64, 128, 1, 1, F_CD16><<<dim3(8, 16, 8), TPB, 0, stream>>>(
          gb, 64, 4096, 4096, 1024, 0.125f, 0);
    }
    // K3: per-row softmax stats
    rowlse_h<<<2048, TPB, 0, stream>>>(Sh, Mrw, Inv);
    // K4T: oT[pos][4*d+h] = sum_kv P * v ; K split in halves -> oAh/oBh
    // BM=32 -> 512 blocks (2/CU) for latency hiding
    {
      GBN gb{};
      for (int kh = 0; kh < 2; ++kh)
        for (int imh = 0; imh < 8; ++imh) {
          int im = imh >> 2, h = imh & 3;
          gb.g[kh * 8 + imh] = mkgb(Sh + (size_t)imh * 1048576 + kh * 512,
                                    qkvh + (size_t)(im * 3 + 2) * DSTR + h * 1024 + kh * 512,
                                    (kh ? oBh : oAh) + (size_t)im * 262144,
                                    nullptr, nullptr, nullptr,
                                    Mrw + imh * 1024, Inv + imh * 1024, h);
        }
      gemmh<32, 64, 2, 2, F_CD16 | F_CSCAT><<<dim3(1, 32, 16), TPB, 0, stream>>>(
          gb, 512, 1024, 4096, 256, 1.f, 0);
    }
    // K6': tb = [W0a|Wf] x [x; oA+oB] + bf ; epilogue accumulates row stats
    {
      GBN gb{};
      for (int im = 0; im < 2; ++im)
        gb.g[im] = mkgb(mlp_w0 + (size_t)i * 262144, xs[im],
                        tbh + (size_t)im * 524288, bfB + (size_t)i * 512,
                        oAh + (size_t)im * 262144, nullptr,
                        SS1 + (size_t)i * 1024 + im * 512,
                        SS2 + (size_t)i * 1024 + im * 512,
                        0, WfB + (size_t)i * 131072, oBh + (size_t)im * 262144);
      gemmh<64, 64, 0, 0, F_CD16 | F_ACONCAT | F_BMIX | F_STATS>
          <<<dim3(16, 8, 2), TPB, 0, stream>>>(
          gb, 512, 512, 1024, 1024, 1.f, 256);
    }
    // K8: mlp1 with inorm+relu from raw sums, fp32 residual -> dn
    {
      GBN gb{};
      for (int im = 0; im < 2; ++im)
        gb.g[im] = mkgb(mlp_w1 + (size_t)i * 131072, tbh + (size_t)im * 524288,
                        dn + (size_t)im * DSTR, mlp_b1 + (size_t)i * 256,
                        nullptr, xs[im],
                        SS1 + (size_t)i * 1024 + im * 512,
                        SS2 + (size_t)i * 1024 + im * 512);
      gemmh<32, 64, 0, 1, F_BNORM2 | F_RES><<<dim3(16, 8, 2), TPB, 0, stream>>>(
          gb, 512, 512, 1024, 1024, 1.f, 0);
    }
    float* tmp = dc; dc = dn; dn = tmp;
  }

  // ---- final projection -> mdbh f16 ----
  {
    GBN gb{};
    for (int im = 0; im < 2; ++im)
      gb.g[im] = mkgb(final_w, dc + (size_t)im * DSTR, mdbh + (size_t)im * 262144,
                      final_b);
    gemmh<32, 64, 0, 0, F_CD16><<<dim3(16, 8, 2), TPB, 0, stream>>>(
        gb, 256, 256, 1024, 1024, 1.f, 0);
  }
  // ---- scores -> Zb fp32 + Zh/Zth f16 ----
  {
    GBN gb{};
    gb.g[0] = mkgb(mdbh, mdbh + 262144, Zb, nullptr, nullptr, nullptr,
                   nullptr, nullptr, 0, Zh, Zth);
    gemmh<64, 64, 1, 1, F_OUT2><<<dim3(16, 16, 1), TPB, 0, stream>>>(
        gb, 256, 1024, 1024, ZLD, 0.0625f, 0);
  }
  fill_bins<<<5, TPB, 0, stream>>>(Zb, alpha_p, uS, vS);

  // ---- Sinkhorn: persistent kernel, barrier-free tagged dataflow ----
  sink_persist<<<SINKB, TPB, 0, stream>>>(Zh, Zth, uS, vS, alpha_p);

  // ---- output ----
  assemble<<<4105, TPB, 0, stream>>>(Zb, uS, vS, (float*)d_out);
}